// Round 1
// baseline (16023.325 us; speedup 1.0000x reference)
//
#include <hip/hip_runtime.h>
#include <math.h>

// Problem dims
// B=256, T=64, N=128, M=256, P=256, YD=1
// inputs (B,T,129); WU_e (64,576); v_e (1,64); Wih_e (1024,128); Whh_e (1024,256);
// bih_e/bhh_e (1024); WU_d (256,768); v_d (1,256); wb_tilde (1,257); Wih_d (1024,1);
// Whh_d (1024,256); bih_d/bhh_d (1024); Wb_W (256,512); Wb_b (256); vb_W (1,256); vb_b (1)

// Workspace layout (float offsets)
#define OFF_XWT   0u          // [256][64][128]  XWt[b][j][n]
#define OFF_XEWT  2097152u    // [256][256][64]  XeWt[b][j][t']
#define OFF_XE    6291456u    // [256][64][256]  Xe[b][t][m]
#define OFF_HE    10485760u   // [2][256][256]
#define OFF_CE    10616832u
#define OFF_HD    10747904u
#define OFF_CD    10878976u
#define OFF_SP    11010048u   // [16][256][64]   S_part[p][b][j]
#define OFF_SDP   11272192u   // [16][256][256]  Sd_part[p][b][j]
#define OFF_XA    12320768u   // [256][128]
#define OFF_CTX   12353536u   // [256][256]
#define OFF_YT    12419072u   // [256]
#define OFF_BAR   12419328u   // 16 groups x 16 u32
#define WS_END    12419584u

__device__ __forceinline__ float fast_tanh(float x) {
  float xc = fminf(15.f, fmaxf(-15.f, x));
  float e = __expf(2.f * xc);
  return 1.f - 2.f * __builtin_amdgcn_rcpf(e + 1.f);
}
__device__ __forceinline__ float fast_sig(float x) {
  float xc = fminf(30.f, fmaxf(-30.f, x));
  return __builtin_amdgcn_rcpf(1.f + __expf(-xc));
}
__device__ __forceinline__ float wave_max(float v) {
#pragma unroll
  for (int o = 32; o; o >>= 1) v = fmaxf(v, __shfl_xor(v, o));
  return v;
}
__device__ __forceinline__ float wave_sum(float v) {
#pragma unroll
  for (int o = 32; o; o >>= 1) v += __shfl_xor(v, o);
  return v;
}
__device__ __forceinline__ float dot4(float4 a, float4 b) {
  return a.x*b.x + a.y*b.y + a.z*b.z + a.w*b.w;
}

// acc_bs.(g) += xv.(bs) * wv.(g)
#define FMA16(a0,a1,a2,a3,xv,wv) \
  a0.x += xv.x*wv.x; a0.y += xv.x*wv.y; a0.z += xv.x*wv.z; a0.w += xv.x*wv.w; \
  a1.x += xv.y*wv.x; a1.y += xv.y*wv.y; a1.z += xv.y*wv.z; a1.w += xv.y*wv.w; \
  a2.x += xv.z*wv.x; a2.y += xv.z*wv.y; a2.z += xv.z*wv.z; a2.w += xv.z*wv.w; \
  a3.x += xv.w*wv.x; a3.y += xv.w*wv.y; a3.z += xv.w*wv.z; a3.w += xv.w*wv.w;

// 16-block group barrier (groups are fully independent; all ws arrays are per-b)
__device__ __forceinline__ void group_barrier(unsigned* bar) {
  __syncthreads();
  __threadfence();
  if (threadIdx.x == 0) {
    unsigned g = __hip_atomic_load(bar + 1, __ATOMIC_RELAXED, __HIP_MEMORY_SCOPE_AGENT);
    unsigned old = __hip_atomic_fetch_add(bar, 1u, __ATOMIC_ACQ_REL, __HIP_MEMORY_SCOPE_AGENT);
    if (old == 15u) {
      __hip_atomic_store(bar, 0u, __ATOMIC_RELAXED, __HIP_MEMORY_SCOPE_AGENT);
      __hip_atomic_fetch_add(bar + 1, 1u, __ATOMIC_ACQ_REL, __HIP_MEMORY_SCOPE_AGENT);
    } else {
      unsigned cur;
      do {
        __builtin_amdgcn_s_sleep(4);
        cur = __hip_atomic_load(bar + 1, __ATOMIC_RELAXED, __HIP_MEMORY_SCOPE_AGENT);
      } while (cur == g);
    }
  }
  __syncthreads();
  __threadfence();
}

__global__ void darnn_init(float* __restrict__ ws, float* __restrict__ out) {
  unsigned i = blockIdx.x * 256u + threadIdx.x;
  const unsigned span = WS_END - OFF_HE;  // 1,933,824
  for (unsigned idx = i; idx < span; idx += gridDim.x * 256u) ws[OFF_HE + idx] = 0.f;
  if (i < 256u) out[i] = 0.f;
}

__global__ __launch_bounds__(256, 1) void darnn_main(
    const float* __restrict__ in,   const float* __restrict__ WUe,   const float* __restrict__ ve,
    const float* __restrict__ Wih_e,const float* __restrict__ Whh_e,
    const float* __restrict__ bih_e,const float* __restrict__ bhh_e,
    const float* __restrict__ WUd,  const float* __restrict__ vd,
    const float* __restrict__ wbt,  const float* __restrict__ Wih_d,
    const float* __restrict__ Whh_d,const float* __restrict__ bih_d, const float* __restrict__ bhh_d,
    const float* __restrict__ WbW,  const float* __restrict__ Wbb,
    const float* __restrict__ vbW,  const float* __restrict__ vbb,
    float* __restrict__ ws, float* __restrict__ out)
{
  __shared__ __align__(16) char smem_raw[57344];
  float* sm = (float*)smem_raw;
  const int tid = threadIdx.x;
  const int bid = blockIdx.x;
  const int grp = bid >> 4;   // group of 16 blocks = 16 batches
  const int mt  = bid & 15;   // role within group (m-tile / p-tile)
  const int b0  = grp << 4;

  float* XWt  = ws + OFF_XWT;
  float* XeWt = ws + OFF_XEWT;
  float* Xe   = ws + OFF_XE;
  unsigned* barp = (unsigned*)(ws + OFF_BAR) + grp * 16;

  // ---------------- P1: XWt[b][j][n] = sum_k X[b][k][n] * WU_e[j][512+k], b = bid
  {
    float* Xs = sm;  // [n=128][68] transposed X slice (Xs[n][k])
    const float* Xb = in + bid * 8256;
    for (int it = 0; it < 32; ++it) {
      int lin = tid + it * 256;           // 8192 = 64k x 128n
      int k = lin >> 7, n = lin & 127;
      Xs[n * 68 + k] = Xb[k * 129 + n];
    }
    __syncthreads();
    int j = tid & 63, nh = tid >> 6;
    float acc[32];
#pragma unroll
    for (int i = 0; i < 32; ++i) acc[i] = 0.f;
    const float* wrow = WUe + j * 576 + 512;
    for (int kc = 0; kc < 4; ++kc) {
      float4 w0 = *(const float4*)(wrow + kc * 16 + 0);
      float4 w1 = *(const float4*)(wrow + kc * 16 + 4);
      float4 w2 = *(const float4*)(wrow + kc * 16 + 8);
      float4 w3 = *(const float4*)(wrow + kc * 16 + 12);
#pragma unroll
      for (int ni = 0; ni < 32; ++ni) {
        const float* xp = Xs + (nh * 32 + ni) * 68 + kc * 16;
        float4 x0 = *(const float4*)(xp + 0);
        float4 x1 = *(const float4*)(xp + 4);
        float4 x2 = *(const float4*)(xp + 8);
        float4 x3 = *(const float4*)(xp + 12);
        acc[ni] += dot4(x0, w0) + dot4(x1, w1) + dot4(x2, w2) + dot4(x3, w3);
      }
    }
    float* dst = XWt + bid * 8192 + j * 128 + nh * 32;
#pragma unroll
    for (int ni = 0; ni < 32; ++ni) dst[ni] = acc[ni];
    __syncthreads();
  }

  // ================ ENCODER: 64 steps ================
  for (int t = 0; t < 64; ++t) {
    const int rd = t & 1, wr2 = (t + 1) & 1;
    // ---- EA: input attention for b = bid (reads S_part from previous EB)
    {
      float* Sj = sm;        // [64]
      float* Eh = sm + 64;   // [2][128]
      float* r8 = sm + 320;  // [8]
      if (tid < 64) {
        float s = 0.f;
#pragma unroll
        for (int p = 0; p < 16; ++p) s += ws[OFF_SP + (unsigned)(p * 256 + bid) * 64 + tid];
        Sj[tid] = s;
      }
      __syncthreads();
      {
        int n = tid & 127, jh = tid >> 7;
        const float* xwp = XWt + bid * 8192 + n;
        float e = 0.f;
#pragma unroll
        for (int jj = 0; jj < 32; ++jj) {
          int j = (jh << 5) + jj;
          e += ve[j] * fast_tanh(xwp[j << 7] + Sj[j]);
        }
        Eh[(jh << 7) + n] = e;
      }
      __syncthreads();
      int lane = tid & 63, wid = tid >> 6;
      float En = (tid < 128) ? (Eh[tid] + Eh[128 + tid]) : -1e30f;
      float mx = wave_max(En);
      if (lane == 0) r8[wid] = mx;
      __syncthreads();
      mx = fmaxf(fmaxf(r8[0], r8[1]), fmaxf(r8[2], r8[3]));
      float ex = (tid < 128) ? __expf(En - mx) : 0.f;
      float sw = wave_sum(ex);
      if (lane == 0) r8[4 + wid] = sw;
      __syncthreads();
      float tot = r8[4] + r8[5] + r8[6] + r8[7];
      if (tid < 128)
        ws[OFF_XA + bid * 128 + tid] = in[bid * 8256 + t * 129 + tid] * (ex / tot);
    }
    group_barrier(barp);

    // ---- EB: gates GEMM (16b x 16m x 4g, K=384) + LSTM pointwise + S_part for next step
    {
      float* xah = sm;            // [k=384][20]  ([xa|h] transposed, padded)
      float* Wt  = sm + 7680;     // [kk=96][64]  weight chunk, rows = m_loc*4+g
      float* red = Wt;            // alias: [256][16] after k-loop
      float* hcs = sm + 13824;    // [16][32]  h_new | c_new
      {
        int bl = tid >> 4, kof = tid & 15;
#pragma unroll
        for (int it = 0; it < 24; ++it) {
          int k = kof + it * 16;
          float v = (k < 128) ? ws[OFF_XA + (unsigned)(b0 + bl) * 128 + k]
                              : ws[OFF_HE + (unsigned)rd * 65536 + (unsigned)(b0 + bl) * 256 + (k - 128)];
          xah[k * 20 + bl] = v;
        }
      }
      const int ks = tid >> 6, ml = (tid >> 2) & 15, b4 = tid & 3;
      float4 a0 = {0,0,0,0}, a1 = {0,0,0,0}, a2 = {0,0,0,0}, a3 = {0,0,0,0};
      for (int c = 0; c < 4; ++c) {
        __syncthreads();
        {  // stage Wt chunk c (96 k)
          int r = tid & 63, kq = tid >> 6;
          int grow = (r & 3) * 256 + mt * 16 + (r >> 2);
#pragma unroll
          for (int q = 0; q < 6; ++q) {
            int kkl = kq * 24 + q * 4;
            int k = c * 96 + kkl;
            float4 wv = (k < 128) ? *(const float4*)(Wih_e + grow * 128 + k)
                                  : *(const float4*)(Whh_e + grow * 256 + (k - 128));
            Wt[(kkl + 0) * 64 + r] = wv.x; Wt[(kkl + 1) * 64 + r] = wv.y;
            Wt[(kkl + 2) * 64 + r] = wv.z; Wt[(kkl + 3) * 64 + r] = wv.w;
          }
        }
        __syncthreads();
        int kk0 = ks * 24;
#pragma unroll 8
        for (int kk = 0; kk < 24; ++kk) {
          int kg = c * 96 + kk0 + kk;
          float4 xv = *(const float4*)(xah + kg * 20 + b4 * 4);
          float4 wv = *(const float4*)(Wt + (kk0 + kk) * 64 + ml * 4);
          FMA16(a0, a1, a2, a3, xv, wv);
        }
      }
      __syncthreads();
      {
        int tIdx = ml * 4 + b4;
        float* rp = red + (unsigned)(ks * 64 + tIdx) * 16;
        *(float4*)(rp + 0) = a0; *(float4*)(rp + 4) = a1;
        *(float4*)(rp + 8) = a2; *(float4*)(rp + 12) = a3;
      }
      __syncthreads();
      {  // combine + pointwise; thread = (b_loc, m_loc)
        int bl = tid & 15, m2 = tid >> 4;
        int t2 = m2 * 4 + (bl >> 2), bs = bl & 3;
        float4 gate = {0,0,0,0};
#pragma unroll
        for (int k2 = 0; k2 < 4; ++k2) {
          float4 rr = *(const float4*)(red + (unsigned)(k2 * 64 + t2) * 16 + bs * 4);
          gate.x += rr.x; gate.y += rr.y; gate.z += rr.z; gate.w += rr.w;
        }
        int m = mt * 16 + m2;
        float gi = gate.x + bih_e[m]       + bhh_e[m];
        float gf = gate.y + bih_e[256 + m] + bhh_e[256 + m];
        float gg = gate.z + bih_e[512 + m] + bhh_e[512 + m];
        float go = gate.w + bih_e[768 + m] + bhh_e[768 + m];
        unsigned bi = (unsigned)(b0 + bl) * 256 + m;
        float co = ws[OFF_CE + (unsigned)rd * 65536 + bi];
        float cn = fast_sig(gf) * co + fast_sig(gi) * fast_tanh(gg);
        float hn = fast_sig(go) * fast_tanh(cn);
        ws[OFF_HE + (unsigned)wr2 * 65536 + bi] = hn;
        ws[OFF_CE + (unsigned)wr2 * 65536 + bi] = cn;
        Xe[((unsigned)(b0 + bl) * 64 + t) * 256 + m] = hn;
        hcs[bl * 32 + m2] = hn;
        hcs[bl * 32 + 16 + m2] = cn;
      }
      __syncthreads();
      {  // S_part[mt][b][j] for next step's EA
        int j = tid & 63, wq = tid >> 6;
        const float* wre = WUe + j * 576 + mt * 16;
        float4 wh[4], wc[4];
#pragma unroll
        for (int q = 0; q < 4; ++q) {
          wh[q] = *(const float4*)(wre + q * 4);
          wc[q] = *(const float4*)(wre + 256 + q * 4);
        }
#pragma unroll
        for (int bs2 = 0; bs2 < 4; ++bs2) {
          int bl2 = wq * 4 + bs2;
          const float* hp = hcs + bl2 * 32;
          float s = 0.f;
#pragma unroll
          for (int q = 0; q < 4; ++q) {
            float4 hv = *(const float4*)(hp + q * 4);
            float4 cv = *(const float4*)(hp + 16 + q * 4);
            s += dot4(hv, wh[q]) + dot4(cv, wc[q]);
          }
          ws[OFF_SP + (unsigned)(mt * 256 + b0 + bl2) * 64 + j] = s;
        }
      }
    }
    group_barrier(barp);
  }

  // ---------------- P2: XeWt[b][j][t'] = sum_k Xe[b][t'][k] * WU_d[j][512+k], b = bid
  {
    float* XeT = sm;          // [kk=64][68] (XeT[kk][t'])
    float* Wdc = sm + 4352;   // [kk=64][68] (Wdc[kk][jj])
    int tt2 = tid & 15, jq = tid >> 4;
    for (int jc = 0; jc < 4; ++jc) {
      float4 c0 = {0,0,0,0}, c1 = {0,0,0,0}, c2 = {0,0,0,0}, c3 = {0,0,0,0};
      for (int kc = 0; kc < 4; ++kc) {
        __syncthreads();
        for (int it = 0; it < 16; ++it) {
          int lin = tid + it * 256;  // 4096 = 64t x 64k
          int tt3 = lin >> 6, kk = lin & 63;
          XeT[kk * 68 + tt3] = Xe[((unsigned)bid * 64 + tt3) * 256 + kc * 64 + kk];
        }
        for (int it = 0; it < 16; ++it) {
          int lin = tid + it * 256;
          int jj = lin >> 6, kk = lin & 63;
          Wdc[kk * 68 + jj] = WUd[(unsigned)(jc * 64 + jj) * 768 + 512 + kc * 64 + kk];
        }
        __syncthreads();
#pragma unroll 8
        for (int kk = 0; kk < 64; ++kk) {
          float4 xv = *(const float4*)(XeT + kk * 68 + tt2 * 4);
          float4 wv = *(const float4*)(Wdc + kk * 68 + jq * 4);
          FMA16(c0, c1, c2, c3, wv, xv);  // c_jx.(ti) += wv.(jx)*xv.(ti)
        }
      }
      {
        int jb = jc * 64 + jq * 4;
        *(float4*)(XeWt + ((unsigned)bid * 256 + jb + 0) * 64 + tt2 * 4) = c0;
        *(float4*)(XeWt + ((unsigned)bid * 256 + jb + 1) * 64 + tt2 * 4) = c1;
        *(float4*)(XeWt + ((unsigned)bid * 256 + jb + 2) * 64 + tt2 * 4) = c2;
        *(float4*)(XeWt + ((unsigned)bid * 256 + jb + 3) * 64 + tt2 * 4) = c3;
      }
    }
    __syncthreads();
  }

  // ================ DECODER: 63 steps ================
  for (int t = 0; t < 63; ++t) {
    const int rd = t & 1, wr2 = (t + 1) & 1;
    // ---- DA: temporal attention + ctx + y_tilde for b = bid
    {
      float* Sdj  = sm;        // [256]
      float* lp   = sm + 256;  // [4][64]
      float* beta = sm + 512;  // [64]
      float* r8   = sm + 576;  // [8]
      {
        float s = 0.f;
#pragma unroll
        for (int p = 0; p < 16; ++p) s += ws[OFF_SDP + (unsigned)(p * 256 + bid) * 256 + tid];
        Sdj[tid] = s;
      }
      __syncthreads();
      {
        int tq = tid & 63, q = tid >> 6;
        const float* xew = XeWt + (unsigned)bid * 16384 + tq;
        float l = 0.f;
#pragma unroll 8
        for (int jj = 0; jj < 64; ++jj) {
          int j = q * 64 + jj;
          l += vd[j] * fast_tanh(xew[j << 6] + Sdj[j]);
        }
        lp[q * 64 + tq] = l;
      }
      __syncthreads();
      if (tid < 64) {
        float lv = lp[tid] + lp[64 + tid] + lp[128 + tid] + lp[192 + tid];
        float mx = wave_max(lv);
        float ex = __expf(lv - mx);
        float sw = wave_sum(ex);
        beta[tid] = ex / sw;
      }
      __syncthreads();
      {
        float acc = 0.f;
        const float* xep = Xe + (unsigned)bid * 16384 + tid;
#pragma unroll 8
        for (int tt3 = 0; tt3 < 64; ++tt3) acc += beta[tt3] * xep[tt3 << 8];
        ws[OFF_CTX + (unsigned)bid * 256 + tid] = acc;
        float yp = acc * wbt[1 + tid];
        float swv = wave_sum(yp);
        if ((tid & 63) == 0) r8[tid >> 6] = swv;
      }
      __syncthreads();
      if (tid == 0) {
        float yt = wbt[0] * in[bid * 8256 + t * 129 + 128] + r8[0] + r8[1] + r8[2] + r8[3];
        ws[OFF_YT + bid] = yt;
      }
    }
    group_barrier(barp);

    // ---- DB: decoder gates GEMM (K=256) + pointwise + Sd_part for next step
    {
      float* hT  = sm;            // [k=256][20]
      float* Wt  = sm + 5120;     // [kk=128][64]
      float* red = Wt;            // alias [256][16]
      float* hcs = sm + 13312;    // [16][32]
      {
        int bl = tid >> 4, kof = tid & 15;
#pragma unroll
        for (int it = 0; it < 16; ++it) {
          int k = kof + it * 16;
          hT[k * 20 + bl] = ws[OFF_HD + (unsigned)rd * 65536 + (unsigned)(b0 + bl) * 256 + k];
        }
      }
      const int ks = tid >> 6, ml = (tid >> 2) & 15, b4 = tid & 3;
      float4 a0 = {0,0,0,0}, a1 = {0,0,0,0}, a2 = {0,0,0,0}, a3 = {0,0,0,0};
      for (int c = 0; c < 2; ++c) {
        __syncthreads();
        {
          int r = tid & 63, kq = tid >> 6;
          int grow = (r & 3) * 256 + mt * 16 + (r >> 2);
#pragma unroll
          for (int q = 0; q < 8; ++q) {
            int kkl = kq * 32 + q * 4;
            float4 wv = *(const float4*)(Whh_d + grow * 256 + c * 128 + kkl);
            Wt[(kkl + 0) * 64 + r] = wv.x; Wt[(kkl + 1) * 64 + r] = wv.y;
            Wt[(kkl + 2) * 64 + r] = wv.z; Wt[(kkl + 3) * 64 + r] = wv.w;
          }
        }
        __syncthreads();
        int kk0 = ks * 32;
#pragma unroll 8
        for (int kk = 0; kk < 32; ++kk) {
          int kg = c * 128 + kk0 + kk;
          float4 xv = *(const float4*)(hT + kg * 20 + b4 * 4);
          float4 wv = *(const float4*)(Wt + (kk0 + kk) * 64 + ml * 4);
          FMA16(a0, a1, a2, a3, xv, wv);
        }
      }
      __syncthreads();
      {
        int tIdx = ml * 4 + b4;
        float* rp = red + (unsigned)(ks * 64 + tIdx) * 16;
        *(float4*)(rp + 0) = a0; *(float4*)(rp + 4) = a1;
        *(float4*)(rp + 8) = a2; *(float4*)(rp + 12) = a3;
      }
      __syncthreads();
      {
        int bl = tid & 15, m2 = tid >> 4;
        int t2 = m2 * 4 + (bl >> 2), bs = bl & 3;
        float4 gate = {0,0,0,0};
#pragma unroll
        for (int k2 = 0; k2 < 4; ++k2) {
          float4 rr = *(const float4*)(red + (unsigned)(k2 * 64 + t2) * 16 + bs * 4);
          gate.x += rr.x; gate.y += rr.y; gate.z += rr.z; gate.w += rr.w;
        }
        int m = mt * 16 + m2;
        float yt = ws[OFF_YT + b0 + bl];
        float gi = gate.x + yt * Wih_d[m]       + bih_d[m]       + bhh_d[m];
        float gf = gate.y + yt * Wih_d[256 + m] + bih_d[256 + m] + bhh_d[256 + m];
        float gg = gate.z + yt * Wih_d[512 + m] + bih_d[512 + m] + bhh_d[512 + m];
        float go = gate.w + yt * Wih_d[768 + m] + bih_d[768 + m] + bhh_d[768 + m];
        unsigned bi = (unsigned)(b0 + bl) * 256 + m;
        float co = ws[OFF_CD + (unsigned)rd * 65536 + bi];
        float cn = fast_sig(gf) * co + fast_sig(gi) * fast_tanh(gg);
        float hn = fast_sig(go) * fast_tanh(cn);
        ws[OFF_HD + (unsigned)wr2 * 65536 + bi] = hn;
        ws[OFF_CD + (unsigned)wr2 * 65536 + bi] = cn;
        hcs[bl * 32 + m2] = hn;
        hcs[bl * 32 + 16 + m2] = cn;
      }
      __syncthreads();
      {  // Sd_part[mt][b][j], j = tid (256 rows of WU_d)
        int j = tid;
        const float* wrd = WUd + (unsigned)j * 768 + mt * 16;
        float4 wh[4], wc[4];
#pragma unroll
        for (int q = 0; q < 4; ++q) {
          wh[q] = *(const float4*)(wrd + q * 4);
          wc[q] = *(const float4*)(wrd + 256 + q * 4);
        }
#pragma unroll 4
        for (int bl2 = 0; bl2 < 16; ++bl2) {
          const float* hp = hcs + bl2 * 32;
          float s = 0.f;
#pragma unroll
          for (int q = 0; q < 4; ++q) {
            float4 hv = *(const float4*)(hp + q * 4);
            float4 cv = *(const float4*)(hp + 16 + q * 4);
            s += dot4(hv, wh[q]) + dot4(cv, wc[q]);
          }
          ws[OFF_SDP + (unsigned)(mt * 256 + b0 + bl2) * 256 + j] = s;
        }
      }
    }
    group_barrier(barp);
  }

  // ---------------- FINAL: hidden = [h_d, ctx] @ Wb_W.T + Wb_b; y = hidden @ vb_W.T + vb_b
  {
    float* hsf  = sm;          // [16][516]
    float* hidw = sm + 8256;   // [16][17]
    for (int it = 0; it < 32; ++it) {
      int lin = tid + it * 256;  // 8192 = 16b x 512k
      int bl = lin >> 9, k = lin & 511;
      float v = (k < 256) ? ws[OFF_HD + 65536u + (unsigned)(b0 + bl) * 256 + k]  // last buf = 1
                          : ws[OFF_CTX + (unsigned)(b0 + bl) * 256 + (k - 256)];
      hsf[bl * 516 + k] = v;
    }
    __syncthreads();
    int bl = tid & 15, p4 = tid >> 4;
    int row = mt * 16 + p4;
    const float* wrow = WbW + (unsigned)row * 512;
    const float* hp = hsf + bl * 516;
    float acc = Wbb[row];
#pragma unroll 8
    for (int q = 0; q < 128; ++q) {
      float4 hv = *(const float4*)(hp + q * 4);
      float4 wv = *(const float4*)(wrow + q * 4);
      acc += dot4(hv, wv);
    }
    hidw[bl * 17 + p4] = acc * vbW[row];
    __syncthreads();
    if (tid < 16) {
      float s = 0.f;
#pragma unroll
      for (int p = 0; p < 16; ++p) s += hidw[tid * 17 + p];
      if (mt == 0) s += vbb[0];
      atomicAdd(&out[b0 + tid], s);
    }
  }
}

extern "C" void kernel_launch(void* const* d_in, const int* in_sizes, int n_in,
                              void* d_out, int out_size, void* d_ws, size_t ws_size,
                              hipStream_t stream) {
  (void)in_sizes; (void)n_in; (void)out_size; (void)ws_size;
  const float* in    = (const float*)d_in[0];
  const float* WUe   = (const float*)d_in[1];
  const float* ve    = (const float*)d_in[2];
  const float* Wih_e = (const float*)d_in[3];
  const float* Whh_e = (const float*)d_in[4];
  const float* bih_e = (const float*)d_in[5];
  const float* bhh_e = (const float*)d_in[6];
  const float* WUd   = (const float*)d_in[7];
  const float* vd    = (const float*)d_in[8];
  const float* wbt   = (const float*)d_in[9];
  const float* Wih_d = (const float*)d_in[10];
  const float* Whh_d = (const float*)d_in[11];
  const float* bih_d = (const float*)d_in[12];
  const float* bhh_d = (const float*)d_in[13];
  const float* WbW   = (const float*)d_in[14];
  const float* Wbb   = (const float*)d_in[15];
  const float* vbW   = (const float*)d_in[16];
  const float* vbb   = (const float*)d_in[17];
  float* ws  = (float*)d_ws;
  float* out = (float*)d_out;

  hipLaunchKernelGGL(darnn_init, dim3(1024), dim3(256), 0, stream, ws, out);
  hipLaunchKernelGGL(darnn_main, dim3(256), dim3(256), 0, stream,
                     in, WUe, ve, Wih_e, Whh_e, bih_e, bhh_e,
                     WUd, vd, wbt, Wih_d, Whh_d, bih_d, bhh_d,
                     WbW, Wbb, vbW, vbb, ws, out);
}

// Round 2
// 2698.395 us; speedup vs baseline: 5.9381x; 5.9381x over previous
//
#include <hip/hip_runtime.h>
#include <math.h>

// Problem dims
// B=256, T=64, N=128, M=256, P=256, YD=1

// Workspace layout (float offsets)
#define OFF_XWT   0u          // [256][64][128]  XWt[b][j][n]         (block-local)
#define OFF_XEWT  2097152u    // [256][256][64]  XeWt[b][j][t']       (block-local)
#define OFF_XE    6291456u    // [256][64][256]  Xe[b][t][m]          (sc1 write once, normal read)
#define OFF_HE    10485760u   // [2][256][256]   h_e                  (sc1 w/r)
#define OFF_CE    10616832u   //                 c_e                  (block-local)
#define OFF_HD    10747904u   //                 h_d                  (sc1 w/r)
#define OFF_CD    10878976u   //                 c_d                  (block-local)
#define OFF_SP    11010048u   // [16][256][64]   S_part[p][b][j]      (sc1 w/r)
#define OFF_SDP   11272192u   // [16][256][256]  Sd_part[p][b][j]     (sc1 w/r)
#define OFF_XA    12320768u   // [256][128]      x*alpha              (sc1 w/r)
#define OFF_CTX   12353536u   // [256][256]      ctx                  (sc1 w/r)
#define OFF_YT    12419072u   // [256]           y_tilde              (sc1 w/r)
#define OFF_BAR   12419328u   // 16 groups x 32 u32 (128B apart)
#define WS_END    12419840u

__device__ __forceinline__ float fast_tanh(float x) {
  float xc = fminf(15.f, fmaxf(-15.f, x));
  float e = __expf(2.f * xc);
  return 1.f - 2.f * __builtin_amdgcn_rcpf(e + 1.f);
}
__device__ __forceinline__ float fast_sig(float x) {
  float xc = fminf(30.f, fmaxf(-30.f, x));
  return __builtin_amdgcn_rcpf(1.f + __expf(-xc));
}
__device__ __forceinline__ float wave_max(float v) {
#pragma unroll
  for (int o = 32; o; o >>= 1) v = fmaxf(v, __shfl_xor(v, o));
  return v;
}
__device__ __forceinline__ float wave_sum(float v) {
#pragma unroll
  for (int o = 32; o; o >>= 1) v += __shfl_xor(v, o);
  return v;
}
__device__ __forceinline__ float dot4(float4 a, float4 b) {
  return a.x*b.x + a.y*b.y + a.z*b.z + a.w*b.w;
}

// ---- device-scope (sc1) coherent access helpers: bypass L1/L2, served at IC ----
__device__ __forceinline__ void st1_sc1(float* p, float v) {
  asm volatile("global_store_dword %0, %1, off sc1" :: "v"(p), "v"(v) : "memory");
}
__device__ __forceinline__ float ld1_sc1(const float* p) {
  float v;
  asm volatile("global_load_dword %0, %1, off sc1\n\ts_waitcnt vmcnt(0)"
               : "=v"(v) : "v"(p) : "memory");
  return v;
}
__device__ __forceinline__ void ld1q_sc1(float4& a, const float* pa) {
  asm volatile("global_load_dwordx4 %0, %1, off sc1\n\ts_waitcnt vmcnt(0)"
               : "=&v"(a) : "v"(pa) : "memory");
}
__device__ __forceinline__ void ld4q_sc1(float4& a, float4& b, float4& c, float4& d,
    const float* pa, const float* pb, const float* pc, const float* pd) {
  asm volatile(
      "global_load_dwordx4 %0, %4, off sc1\n\t"
      "global_load_dwordx4 %1, %5, off sc1\n\t"
      "global_load_dwordx4 %2, %6, off sc1\n\t"
      "global_load_dwordx4 %3, %7, off sc1\n\t"
      "s_waitcnt vmcnt(0)"
      : "=&v"(a), "=&v"(b), "=&v"(c), "=&v"(d)
      : "v"(pa), "v"(pb), "v"(pc), "v"(pd) : "memory");
}
__device__ __forceinline__ void ld6q_sc1(float4& a, float4& b, float4& c,
    float4& d, float4& e, float4& f,
    const float* pa, const float* pb, const float* pc,
    const float* pd, const float* pe, const float* pf) {
  asm volatile(
      "global_load_dwordx4 %0, %6, off sc1\n\t"
      "global_load_dwordx4 %1, %7, off sc1\n\t"
      "global_load_dwordx4 %2, %8, off sc1\n\t"
      "global_load_dwordx4 %3, %9, off sc1\n\t"
      "global_load_dwordx4 %4, %10, off sc1\n\t"
      "global_load_dwordx4 %5, %11, off sc1\n\t"
      "s_waitcnt vmcnt(0)"
      : "=&v"(a), "=&v"(b), "=&v"(c), "=&v"(d), "=&v"(e), "=&v"(f)
      : "v"(pa), "v"(pb), "v"(pc), "v"(pd), "v"(pe), "v"(pf) : "memory");
}

// acc_bs.(g) += xv.(bs) * wv.(g)
#define FMA16(a0,a1,a2,a3,xv,wv) \
  a0.x += xv.x*wv.x; a0.y += xv.x*wv.y; a0.z += xv.x*wv.z; a0.w += xv.x*wv.w; \
  a1.x += xv.y*wv.x; a1.y += xv.y*wv.y; a1.z += xv.y*wv.z; a1.w += xv.y*wv.w; \
  a2.x += xv.z*wv.x; a2.y += xv.z*wv.y; a2.z += xv.z*wv.z; a2.w += xv.z*wv.w; \
  a3.x += xv.w*wv.x; a3.y += xv.w*wv.y; a3.z += xv.w*wv.z; a3.w += xv.w*wv.w;

// Fence-free 16-block group barrier: monotonic arrival counter via relaxed
// agent-scope (sc1) atomics. No wbl2/inv -> L2 stays hot. Per-wave vmcnt(0)
// before s_barrier guarantees all sc1 data stores are globally visible before
// the flag increment (data and flag meet at the same coherent point).
__device__ __forceinline__ void group_barrier(unsigned* bar, unsigned& n) {
  n += 16;
  asm volatile("s_waitcnt vmcnt(0)" ::: "memory");
  __syncthreads();
  if (threadIdx.x == 0) {
    __hip_atomic_fetch_add(bar, 1u, __ATOMIC_RELAXED, __HIP_MEMORY_SCOPE_AGENT);
    unsigned cur;
    do {
      cur = __hip_atomic_load(bar, __ATOMIC_RELAXED, __HIP_MEMORY_SCOPE_AGENT);
    } while (cur < n);
  }
  __syncthreads();
}

__global__ void darnn_init(float* __restrict__ ws, float* __restrict__ out) {
  unsigned i = blockIdx.x * 256u + threadIdx.x;
  const unsigned span = WS_END - OFF_HE;
  for (unsigned idx = i; idx < span; idx += gridDim.x * 256u) ws[OFF_HE + idx] = 0.f;
  if (i < 256u) out[i] = 0.f;
}

__global__ __launch_bounds__(256, 1) void darnn_main(
    const float* __restrict__ in,   const float* __restrict__ WUe,   const float* __restrict__ ve,
    const float* __restrict__ Wih_e,const float* __restrict__ Whh_e,
    const float* __restrict__ bih_e,const float* __restrict__ bhh_e,
    const float* __restrict__ WUd,  const float* __restrict__ vd,
    const float* __restrict__ wbt,  const float* __restrict__ Wih_d,
    const float* __restrict__ Whh_d,const float* __restrict__ bih_d, const float* __restrict__ bhh_d,
    const float* __restrict__ WbW,  const float* __restrict__ Wbb,
    const float* __restrict__ vbW,  const float* __restrict__ vbb,
    float* __restrict__ ws, float* __restrict__ out)
{
  __shared__ __align__(16) char smem_raw[57344];
  float* sm = (float*)smem_raw;
  const int tid = threadIdx.x;
  const int bid = blockIdx.x;
  const int grp = bid >> 4;   // group of 16 blocks = 16 batches
  const int mt  = bid & 15;   // role within group (m-tile / p-tile)
  const int b0  = grp << 4;

  float* XWt  = ws + OFF_XWT;
  float* XeWt = ws + OFF_XEWT;
  float* Xe   = ws + OFF_XE;
  unsigned* barp = (unsigned*)(ws + OFF_BAR) + grp * 32;
  unsigned barn = 0;

  // ---------------- P1: XWt[b][j][n] = sum_k X[b][k][n] * WU_e[j][512+k], b = bid
  {
    float* Xs = sm;  // [n=128][68]
    const float* Xb = in + bid * 8256;
    for (int it = 0; it < 32; ++it) {
      int lin = tid + it * 256;
      int k = lin >> 7, n = lin & 127;
      Xs[n * 68 + k] = Xb[k * 129 + n];
    }
    __syncthreads();
    int j = tid & 63, nh = tid >> 6;
    float acc[32];
#pragma unroll
    for (int i = 0; i < 32; ++i) acc[i] = 0.f;
    const float* wrow = WUe + j * 576 + 512;
    for (int kc = 0; kc < 4; ++kc) {
      float4 w0 = *(const float4*)(wrow + kc * 16 + 0);
      float4 w1 = *(const float4*)(wrow + kc * 16 + 4);
      float4 w2 = *(const float4*)(wrow + kc * 16 + 8);
      float4 w3 = *(const float4*)(wrow + kc * 16 + 12);
#pragma unroll
      for (int ni = 0; ni < 32; ++ni) {
        const float* xp = Xs + (nh * 32 + ni) * 68 + kc * 16;
        float4 x0 = *(const float4*)(xp + 0);
        float4 x1 = *(const float4*)(xp + 4);
        float4 x2 = *(const float4*)(xp + 8);
        float4 x3 = *(const float4*)(xp + 12);
        acc[ni] += dot4(x0, w0) + dot4(x1, w1) + dot4(x2, w2) + dot4(x3, w3);
      }
    }
    float* dst = XWt + bid * 8192 + j * 128 + nh * 32;
#pragma unroll
    for (int ni = 0; ni < 32; ++ni) dst[ni] = acc[ni];
    __syncthreads();
  }

  // ================ ENCODER: 64 steps ================
  for (int t = 0; t < 64; ++t) {
    const int rd = t & 1, wr2 = (t + 1) & 1;
    // ---- EA: input attention for b = bid
    {
      float* Sj  = sm;          // [64]
      float* Ssc = sm + 64;     // [16][64]
      float* Eh  = sm + 1088;   // [2][128]
      float* r8  = sm + 1344;   // [8]
      {
        int p = tid >> 4, j4 = (tid & 15) << 2;
        float4 sv;
        ld1q_sc1(sv, ws + OFF_SP + (unsigned)(p * 256 + bid) * 64 + j4);
        *(float4*)(Ssc + p * 64 + j4) = sv;
      }
      __syncthreads();
      if (tid < 64) {
        float s = 0.f;
#pragma unroll
        for (int p = 0; p < 16; ++p) s += Ssc[p * 64 + tid];
        Sj[tid] = s;
      }
      __syncthreads();
      {
        int n = tid & 127, jh = tid >> 7;
        const float* xwp = XWt + bid * 8192 + n;
        float e = 0.f;
#pragma unroll
        for (int jj = 0; jj < 32; ++jj) {
          int j = (jh << 5) + jj;
          e += ve[j] * fast_tanh(xwp[j << 7] + Sj[j]);
        }
        Eh[(jh << 7) + n] = e;
      }
      __syncthreads();
      int lane = tid & 63, wid = tid >> 6;
      float En = (tid < 128) ? (Eh[tid] + Eh[128 + tid]) : -1e30f;
      float mx = wave_max(En);
      if (lane == 0) r8[wid] = mx;
      __syncthreads();
      mx = fmaxf(fmaxf(r8[0], r8[1]), fmaxf(r8[2], r8[3]));
      float ex = (tid < 128) ? __expf(En - mx) : 0.f;
      float sw = wave_sum(ex);
      if (lane == 0) r8[4 + wid] = sw;
      __syncthreads();
      float tot = r8[4] + r8[5] + r8[6] + r8[7];
      if (tid < 128)
        st1_sc1(ws + OFF_XA + bid * 128 + tid,
                in[bid * 8256 + t * 129 + tid] * (ex / tot));
    }
    group_barrier(barp, barn);

    // ---- EB: gates GEMM (16b x 16m x 4g, K=384) + LSTM pointwise + S_part
    {
      float* xah = sm;            // [k=384][20]
      float* Wt  = sm + 7680;     // [kk=96][64]
      float* red = Wt;            // alias: [256][16]
      float* hcs = sm + 13824;    // [16][32]
      {
        // stage XA (2048 fl) + h (4096 fl) via one sc1 batch of 6 dwordx4
        float4 qv[6]; const float* ps[6]; int kk6[6], bb6[6];
#pragma unroll
        for (int i = 0; i < 2; ++i) {
          int idx = (tid + i * 256) * 4;
          bb6[i] = idx >> 7; kk6[i] = idx & 127;
          ps[i] = ws + OFF_XA + (unsigned)(b0 + bb6[i]) * 128 + kk6[i];
        }
#pragma unroll
        for (int i = 0; i < 4; ++i) {
          int idx = (tid + i * 256) * 4;
          int bl = idx >> 8, k = idx & 255;
          bb6[2 + i] = bl; kk6[2 + i] = 128 + k;
          ps[2 + i] = ws + OFF_HE + (unsigned)rd * 65536 + (unsigned)(b0 + bl) * 256 + k;
        }
        ld6q_sc1(qv[0], qv[1], qv[2], qv[3], qv[4], qv[5],
                 ps[0], ps[1], ps[2], ps[3], ps[4], ps[5]);
#pragma unroll
        for (int i = 0; i < 6; ++i) {
          xah[(kk6[i] + 0) * 20 + bb6[i]] = qv[i].x;
          xah[(kk6[i] + 1) * 20 + bb6[i]] = qv[i].y;
          xah[(kk6[i] + 2) * 20 + bb6[i]] = qv[i].z;
          xah[(kk6[i] + 3) * 20 + bb6[i]] = qv[i].w;
        }
      }
      const int ks = tid >> 6, ml = (tid >> 2) & 15, b4 = tid & 3;
      float4 a0 = {0,0,0,0}, a1 = {0,0,0,0}, a2 = {0,0,0,0}, a3 = {0,0,0,0};
      for (int c = 0; c < 4; ++c) {
        __syncthreads();
        {
          int r = tid & 63, kq = tid >> 6;
          int grow = (r & 3) * 256 + mt * 16 + (r >> 2);
#pragma unroll
          for (int q = 0; q < 6; ++q) {
            int kkl = kq * 24 + q * 4;
            int k = c * 96 + kkl;
            float4 wv = (k < 128) ? *(const float4*)(Wih_e + grow * 128 + k)
                                  : *(const float4*)(Whh_e + grow * 256 + (k - 128));
            Wt[(kkl + 0) * 64 + r] = wv.x; Wt[(kkl + 1) * 64 + r] = wv.y;
            Wt[(kkl + 2) * 64 + r] = wv.z; Wt[(kkl + 3) * 64 + r] = wv.w;
          }
        }
        __syncthreads();
        int kk0 = ks * 24;
#pragma unroll 8
        for (int kk = 0; kk < 24; ++kk) {
          int kg = c * 96 + kk0 + kk;
          float4 xv = *(const float4*)(xah + kg * 20 + b4 * 4);
          float4 wv = *(const float4*)(Wt + (kk0 + kk) * 64 + ml * 4);
          FMA16(a0, a1, a2, a3, xv, wv);
        }
      }
      __syncthreads();
      {
        int tIdx = ml * 4 + b4;
        float* rp = red + (unsigned)(ks * 64 + tIdx) * 16;
        *(float4*)(rp + 0) = a0; *(float4*)(rp + 4) = a1;
        *(float4*)(rp + 8) = a2; *(float4*)(rp + 12) = a3;
      }
      __syncthreads();
      {
        int bl = tid & 15, m2 = tid >> 4;
        int t2 = m2 * 4 + (bl >> 2), bs = bl & 3;
        float4 gate = {0,0,0,0};
#pragma unroll
        for (int k2 = 0; k2 < 4; ++k2) {
          float4 rr = *(const float4*)(red + (unsigned)(k2 * 64 + t2) * 16 + bs * 4);
          gate.x += rr.x; gate.y += rr.y; gate.z += rr.z; gate.w += rr.w;
        }
        int m = mt * 16 + m2;
        float gi = gate.x + bih_e[m]       + bhh_e[m];
        float gf = gate.y + bih_e[256 + m] + bhh_e[256 + m];
        float gg = gate.z + bih_e[512 + m] + bhh_e[512 + m];
        float go = gate.w + bih_e[768 + m] + bhh_e[768 + m];
        unsigned bi = (unsigned)(b0 + bl) * 256 + m;
        float co = ws[OFF_CE + (unsigned)rd * 65536 + bi];
        float cn = fast_sig(gf) * co + fast_sig(gi) * fast_tanh(gg);
        float hn = fast_sig(go) * fast_tanh(cn);
        st1_sc1(ws + OFF_HE + (unsigned)wr2 * 65536 + bi, hn);
        ws[OFF_CE + (unsigned)wr2 * 65536 + bi] = cn;   // block-local
        st1_sc1(Xe + ((unsigned)(b0 + bl) * 64 + t) * 256 + m, hn);
        hcs[bl * 32 + m2] = hn;
        hcs[bl * 32 + 16 + m2] = cn;
      }
      __syncthreads();
      {  // S_part[mt][b][j]
        int j = tid & 63, wq = tid >> 6;
        const float* wre = WUe + j * 576 + mt * 16;
        float4 wh[4], wc[4];
#pragma unroll
        for (int q = 0; q < 4; ++q) {
          wh[q] = *(const float4*)(wre + q * 4);
          wc[q] = *(const float4*)(wre + 256 + q * 4);
        }
#pragma unroll
        for (int bs2 = 0; bs2 < 4; ++bs2) {
          int bl2 = wq * 4 + bs2;
          const float* hp = hcs + bl2 * 32;
          float s = 0.f;
#pragma unroll
          for (int q = 0; q < 4; ++q) {
            float4 hv = *(const float4*)(hp + q * 4);
            float4 cv = *(const float4*)(hp + 16 + q * 4);
            s += dot4(hv, wh[q]) + dot4(cv, wc[q]);
          }
          st1_sc1(ws + OFF_SP + (unsigned)(mt * 256 + b0 + bl2) * 64 + j, s);
        }
      }
    }
    group_barrier(barp, barn);
  }

  // ---------------- P2: XeWt[b][j][t'] = sum_k Xe[b][t'][k] * WU_d[j][512+k]
  {
    float* XeT = sm;          // [kk=64][68]
    float* Wdc = sm + 4352;   // [kk=64][68]
    int tt2 = tid & 15, jq = tid >> 4;
    for (int jc = 0; jc < 4; ++jc) {
      float4 c0 = {0,0,0,0}, c1 = {0,0,0,0}, c2 = {0,0,0,0}, c3 = {0,0,0,0};
      for (int kc = 0; kc < 4; ++kc) {
        __syncthreads();
        for (int it = 0; it < 16; ++it) {
          int lin = tid + it * 256;
          int tt3 = lin >> 6, kk = lin & 63;
          XeT[kk * 68 + tt3] = Xe[((unsigned)bid * 64 + tt3) * 256 + kc * 64 + kk];
        }
        for (int it = 0; it < 16; ++it) {
          int lin = tid + it * 256;
          int jj = lin >> 6, kk = lin & 63;
          Wdc[kk * 68 + jj] = WUd[(unsigned)(jc * 64 + jj) * 768 + 512 + kc * 64 + kk];
        }
        __syncthreads();
#pragma unroll 8
        for (int kk = 0; kk < 64; ++kk) {
          float4 xv = *(const float4*)(XeT + kk * 68 + tt2 * 4);
          float4 wv = *(const float4*)(Wdc + kk * 68 + jq * 4);
          FMA16(c0, c1, c2, c3, wv, xv);
        }
      }
      {
        int jb = jc * 64 + jq * 4;
        *(float4*)(XeWt + ((unsigned)bid * 256 + jb + 0) * 64 + tt2 * 4) = c0;
        *(float4*)(XeWt + ((unsigned)bid * 256 + jb + 1) * 64 + tt2 * 4) = c1;
        *(float4*)(XeWt + ((unsigned)bid * 256 + jb + 2) * 64 + tt2 * 4) = c2;
        *(float4*)(XeWt + ((unsigned)bid * 256 + jb + 3) * 64 + tt2 * 4) = c3;
      }
    }
    __syncthreads();
  }

  // ================ DECODER: 63 steps ================
  for (int t = 0; t < 63; ++t) {
    const int rd = t & 1, wr2 = (t + 1) & 1;
    // ---- DA: temporal attention + ctx + y_tilde for b = bid
    {
      float* Sdj  = sm;        // [256]
      float* lp   = sm + 256;  // [4][64]
      float* beta = sm + 512;  // [64]
      float* r8   = sm + 576;  // [8]
      float* Ssd  = sm + 640;  // [16][256]
      {
        float4 qv[4]; const float* ps[4]; int pp[4], jj[4];
#pragma unroll
        for (int i = 0; i < 4; ++i) {
          int idx = (tid + i * 256) * 4;
          pp[i] = idx >> 8; jj[i] = idx & 255;
          ps[i] = ws + OFF_SDP + (unsigned)(pp[i] * 256 + bid) * 256 + jj[i];
        }
        ld4q_sc1(qv[0], qv[1], qv[2], qv[3], ps[0], ps[1], ps[2], ps[3]);
#pragma unroll
        for (int i = 0; i < 4; ++i) *(float4*)(Ssd + pp[i] * 256 + jj[i]) = qv[i];
      }
      __syncthreads();
      {
        float s = 0.f;
#pragma unroll
        for (int p = 0; p < 16; ++p) s += Ssd[p * 256 + tid];
        Sdj[tid] = s;
      }
      __syncthreads();
      {
        int tq = tid & 63, q = tid >> 6;
        const float* xew = XeWt + (unsigned)bid * 16384 + tq;
        float l = 0.f;
#pragma unroll 8
        for (int jj2 = 0; jj2 < 64; ++jj2) {
          int j = q * 64 + jj2;
          l += vd[j] * fast_tanh(xew[j << 6] + Sdj[j]);
        }
        lp[q * 64 + tq] = l;
      }
      __syncthreads();
      if (tid < 64) {
        float lv = lp[tid] + lp[64 + tid] + lp[128 + tid] + lp[192 + tid];
        float mx = wave_max(lv);
        float ex = __expf(lv - mx);
        float sw = wave_sum(ex);
        beta[tid] = ex / sw;
      }
      __syncthreads();
      {
        float acc = 0.f;
        const float* xep = Xe + (unsigned)bid * 16384 + tid;   // normal read: L2-hot
#pragma unroll 8
        for (int tt3 = 0; tt3 < 64; ++tt3) acc += beta[tt3] * xep[tt3 << 8];
        st1_sc1(ws + OFF_CTX + (unsigned)bid * 256 + tid, acc);
        float yp = acc * wbt[1 + tid];
        float swv = wave_sum(yp);
        if ((tid & 63) == 0) r8[tid >> 6] = swv;
      }
      __syncthreads();
      if (tid == 0) {
        float yt = wbt[0] * in[bid * 8256 + t * 129 + 128] + r8[0] + r8[1] + r8[2] + r8[3];
        st1_sc1(ws + OFF_YT + bid, yt);
      }
    }
    group_barrier(barp, barn);

    // ---- DB: decoder gates GEMM (K=256) + pointwise + Sd_part
    {
      float* hT  = sm;            // [k=256][20]
      float* Wt  = sm + 5120;     // [kk=128][64]
      float* red = Wt;            // alias [256][16]
      float* hcs = sm + 13312;    // [16][32]
      float* yts = sm + 13824;    // [16]
      {
        float4 qv[4]; const float* ps[4]; int kk4[4], bb4[4];
#pragma unroll
        for (int i = 0; i < 4; ++i) {
          int idx = (tid + i * 256) * 4;
          bb4[i] = idx >> 8; kk4[i] = idx & 255;
          ps[i] = ws + OFF_HD + (unsigned)rd * 65536 + (unsigned)(b0 + bb4[i]) * 256 + kk4[i];
        }
        ld4q_sc1(qv[0], qv[1], qv[2], qv[3], ps[0], ps[1], ps[2], ps[3]);
#pragma unroll
        for (int i = 0; i < 4; ++i) {
          hT[(kk4[i] + 0) * 20 + bb4[i]] = qv[i].x;
          hT[(kk4[i] + 1) * 20 + bb4[i]] = qv[i].y;
          hT[(kk4[i] + 2) * 20 + bb4[i]] = qv[i].z;
          hT[(kk4[i] + 3) * 20 + bb4[i]] = qv[i].w;
        }
        if (tid < 16) yts[tid] = ld1_sc1(ws + OFF_YT + b0 + tid);
      }
      const int ks = tid >> 6, ml = (tid >> 2) & 15, b4 = tid & 3;
      float4 a0 = {0,0,0,0}, a1 = {0,0,0,0}, a2 = {0,0,0,0}, a3 = {0,0,0,0};
      for (int c = 0; c < 2; ++c) {
        __syncthreads();
        {
          int r = tid & 63, kq = tid >> 6;
          int grow = (r & 3) * 256 + mt * 16 + (r >> 2);
#pragma unroll
          for (int q = 0; q < 8; ++q) {
            int kkl = kq * 32 + q * 4;
            float4 wv = *(const float4*)(Whh_d + grow * 256 + c * 128 + kkl);
            Wt[(kkl + 0) * 64 + r] = wv.x; Wt[(kkl + 1) * 64 + r] = wv.y;
            Wt[(kkl + 2) * 64 + r] = wv.z; Wt[(kkl + 3) * 64 + r] = wv.w;
          }
        }
        __syncthreads();
        int kk0 = ks * 32;
#pragma unroll 8
        for (int kk = 0; kk < 32; ++kk) {
          int kg = c * 128 + kk0 + kk;
          float4 xv = *(const float4*)(hT + kg * 20 + b4 * 4);
          float4 wv = *(const float4*)(Wt + (kk0 + kk) * 64 + ml * 4);
          FMA16(a0, a1, a2, a3, xv, wv);
        }
      }
      __syncthreads();
      {
        int tIdx = ml * 4 + b4;
        float* rp = red + (unsigned)(ks * 64 + tIdx) * 16;
        *(float4*)(rp + 0) = a0; *(float4*)(rp + 4) = a1;
        *(float4*)(rp + 8) = a2; *(float4*)(rp + 12) = a3;
      }
      __syncthreads();
      {
        int bl = tid & 15, m2 = tid >> 4;
        int t2 = m2 * 4 + (bl >> 2), bs = bl & 3;
        float4 gate = {0,0,0,0};
#pragma unroll
        for (int k2 = 0; k2 < 4; ++k2) {
          float4 rr = *(const float4*)(red + (unsigned)(k2 * 64 + t2) * 16 + bs * 4);
          gate.x += rr.x; gate.y += rr.y; gate.z += rr.z; gate.w += rr.w;
        }
        int m = mt * 16 + m2;
        float yt = yts[bl];
        float gi = gate.x + yt * Wih_d[m]       + bih_d[m]       + bhh_d[m];
        float gf = gate.y + yt * Wih_d[256 + m] + bih_d[256 + m] + bhh_d[256 + m];
        float gg = gate.z + yt * Wih_d[512 + m] + bih_d[512 + m] + bhh_d[512 + m];
        float go = gate.w + yt * Wih_d[768 + m] + bih_d[768 + m] + bhh_d[768 + m];
        unsigned bi = (unsigned)(b0 + bl) * 256 + m;
        float co = ws[OFF_CD + (unsigned)rd * 65536 + bi];
        float cn = fast_sig(gf) * co + fast_sig(gi) * fast_tanh(gg);
        float hn = fast_sig(go) * fast_tanh(cn);
        st1_sc1(ws + OFF_HD + (unsigned)wr2 * 65536 + bi, hn);
        ws[OFF_CD + (unsigned)wr2 * 65536 + bi] = cn;   // block-local
        hcs[bl * 32 + m2] = hn;
        hcs[bl * 32 + 16 + m2] = cn;
      }
      __syncthreads();
      {  // Sd_part[mt][b][j], j = tid
        int j = tid;
        const float* wrd = WUd + (unsigned)j * 768 + mt * 16;
        float4 wh[4], wc[4];
#pragma unroll
        for (int q = 0; q < 4; ++q) {
          wh[q] = *(const float4*)(wrd + q * 4);
          wc[q] = *(const float4*)(wrd + 256 + q * 4);
        }
#pragma unroll 4
        for (int bl2 = 0; bl2 < 16; ++bl2) {
          const float* hp = hcs + bl2 * 32;
          float s = 0.f;
#pragma unroll
          for (int q = 0; q < 4; ++q) {
            float4 hv = *(const float4*)(hp + q * 4);
            float4 cv = *(const float4*)(hp + 16 + q * 4);
            s += dot4(hv, wh[q]) + dot4(cv, wc[q]);
          }
          st1_sc1(ws + OFF_SDP + (unsigned)(mt * 256 + b0 + bl2) * 256 + j, s);
        }
      }
    }
    group_barrier(barp, barn);
  }

  // ---------------- FINAL
  {
    float* hsf  = sm;          // [16][516]
    float* hidw = sm + 8256;   // [16][17]
    for (int half = 0; half < 2; ++half) {
      float4 qv[4]; const float* ps[4]; int kk[4], bb[4];
#pragma unroll
      for (int i = 0; i < 4; ++i) {
        int idx = (tid + (half * 4 + i) * 256) * 4;
        bb[i] = idx >> 9; int k = idx & 511; kk[i] = k;
        ps[i] = (k < 256)
            ? ws + OFF_HD + 65536u + (unsigned)(b0 + bb[i]) * 256 + k
            : ws + OFF_CTX + (unsigned)(b0 + bb[i]) * 256 + (k - 256);
      }
      ld4q_sc1(qv[0], qv[1], qv[2], qv[3], ps[0], ps[1], ps[2], ps[3]);
#pragma unroll
      for (int i = 0; i < 4; ++i) *(float4*)(hsf + bb[i] * 516 + kk[i]) = qv[i];
    }
    __syncthreads();
    int bl = tid & 15, p4 = tid >> 4;
    int row = mt * 16 + p4;
    const float* wrow = WbW + (unsigned)row * 512;
    const float* hp = hsf + bl * 516;
    float acc = Wbb[row];
#pragma unroll 8
    for (int q = 0; q < 128; ++q) {
      float4 hv = *(const float4*)(hp + q * 4);
      float4 wv = *(const float4*)(wrow + q * 4);
      acc += dot4(hv, wv);
    }
    hidw[bl * 17 + p4] = acc * vbW[row];
    __syncthreads();
    if (tid < 16) {
      float s = 0.f;
#pragma unroll
      for (int p = 0; p < 16; ++p) s += hidw[tid * 17 + p];
      if (mt == 0) s += vbb[0];
      atomicAdd(&out[b0 + tid], s);
    }
  }
}

extern "C" void kernel_launch(void* const* d_in, const int* in_sizes, int n_in,
                              void* d_out, int out_size, void* d_ws, size_t ws_size,
                              hipStream_t stream) {
  (void)in_sizes; (void)n_in; (void)out_size; (void)ws_size;
  const float* in    = (const float*)d_in[0];
  const float* WUe   = (const float*)d_in[1];
  const float* ve    = (const float*)d_in[2];
  const float* Wih_e = (const float*)d_in[3];
  const float* Whh_e = (const float*)d_in[4];
  const float* bih_e = (const float*)d_in[5];
  const float* bhh_e = (const float*)d_in[6];
  const float* WUd   = (const float*)d_in[7];
  const float* vd    = (const float*)d_in[8];
  const float* wbt   = (const float*)d_in[9];
  const float* Wih_d = (const float*)d_in[10];
  const float* Whh_d = (const float*)d_in[11];
  const float* bih_d = (const float*)d_in[12];
  const float* bhh_d = (const float*)d_in[13];
  const float* WbW   = (const float*)d_in[14];
  const float* Wbb   = (const float*)d_in[15];
  const float* vbW   = (const float*)d_in[16];
  const float* vbb   = (const float*)d_in[17];
  float* ws  = (float*)d_ws;
  float* out = (float*)d_out;

  hipLaunchKernelGGL(darnn_init, dim3(1024), dim3(256), 0, stream, ws, out);
  hipLaunchKernelGGL(darnn_main, dim3(256), dim3(256), 0, stream,
                     in, WUe, ve, Wih_e, Whh_e, bih_e, bhh_e,
                     WUd, vd, wbt, Wih_d, Whh_d, bih_d, bhh_d,
                     WbW, Wbb, vbW, vbb, ws, out);
}

// Round 3
// 2211.585 us; speedup vs baseline: 7.2452x; 1.2201x over previous
//
#include <hip/hip_runtime.h>
#include <math.h>

// Problem dims: B=256, T=64, N=128, M=256, P=256, YD=1

// Workspace layout (float offsets)
#define OFF_XWT   0u          // [256][64][128]  XWt[b][j][n]         (block-local)
#define OFF_XEWT  2097152u    // [256][256][64]  XeWt[b][j][t']       (block-local)
#define OFF_XE    6291456u    // [256][64][256]  Xe[b][t][m]          (sc1 w / sc1 r once)
#define OFF_HE    10485760u   // [2][256][256]   h_e                  (sc1 w/r)
#define OFF_CE    10616832u   //                 c_e                  (block-local)
#define OFF_HD    10747904u   //                 h_d                  (sc1 w/r)
#define OFF_CD    10878976u   //                 c_d                  (block-local)
#define OFF_SP    11010048u   // [16][256][64]   S_part[p][b][j]      (sc1 w/r)
#define OFF_SDP   11272192u   // [16][256][256]  Sd_part[p][b][j]     (sc1 w/r)
#define OFF_XA    12320768u   // [256][128]      x*alpha              (sc1 w/r)
#define OFF_CTX   12353536u   // [256][256]      ctx                  (sc1 w/r)
#define OFF_YT    12419072u   // [256]           y_tilde              (sc1 w/r)
#define OFF_BAR   12419328u   // 16 groups x 32 u32
#define WS_END    12419840u

// Dynamic LDS layout (floats): weight slab (persistent) + per-phase scratch
#define SLAB_F    24576       // 96 KB: enc W[k*64+r] k<384 / dec W[k*64+r] k<256
#define SCR_F     12288       // 48 KB scratch
#define SMEM_BYTES ((SLAB_F + SCR_F) * 4)

__device__ __forceinline__ float fast_tanh(float x) {
  float xc = fminf(15.f, fmaxf(-15.f, x));
  float e = __expf(2.f * xc);
  return 1.f - 2.f * __builtin_amdgcn_rcpf(e + 1.f);
}
__device__ __forceinline__ float fast_sig(float x) {
  float xc = fminf(30.f, fmaxf(-30.f, x));
  return __builtin_amdgcn_rcpf(1.f + __expf(-xc));
}
__device__ __forceinline__ float wave_max(float v) {
#pragma unroll
  for (int o = 32; o; o >>= 1) v = fmaxf(v, __shfl_xor(v, o));
  return v;
}
__device__ __forceinline__ float wave_sum(float v) {
#pragma unroll
  for (int o = 32; o; o >>= 1) v += __shfl_xor(v, o);
  return v;
}
__device__ __forceinline__ float dot4(float4 a, float4 b) {
  return a.x*b.x + a.y*b.y + a.z*b.z + a.w*b.w;
}

// ---- device-scope (sc1) coherent access helpers ----
__device__ __forceinline__ void st1_sc1(float* p, float v) {
  asm volatile("global_store_dword %0, %1, off sc1" :: "v"(p), "v"(v) : "memory");
}
__device__ __forceinline__ float ld1_sc1(const float* p) {
  float v;
  asm volatile("global_load_dword %0, %1, off sc1\n\ts_waitcnt vmcnt(0)"
               : "=v"(v) : "v"(p) : "memory");
  return v;
}
__device__ __forceinline__ void ld1q_sc1(float4& a, const float* pa) {
  asm volatile("global_load_dwordx4 %0, %1, off sc1\n\ts_waitcnt vmcnt(0)"
               : "=&v"(a) : "v"(pa) : "memory");
}
__device__ __forceinline__ void ld4q_sc1(float4& a, float4& b, float4& c, float4& d,
    const float* pa, const float* pb, const float* pc, const float* pd) {
  asm volatile(
      "global_load_dwordx4 %0, %4, off sc1\n\t"
      "global_load_dwordx4 %1, %5, off sc1\n\t"
      "global_load_dwordx4 %2, %6, off sc1\n\t"
      "global_load_dwordx4 %3, %7, off sc1\n\t"
      "s_waitcnt vmcnt(0)"
      : "=&v"(a), "=&v"(b), "=&v"(c), "=&v"(d)
      : "v"(pa), "v"(pb), "v"(pc), "v"(pd) : "memory");
}
__device__ __forceinline__ void ld6q_sc1(float4& a, float4& b, float4& c,
    float4& d, float4& e, float4& f,
    const float* pa, const float* pb, const float* pc,
    const float* pd, const float* pe, const float* pf) {
  asm volatile(
      "global_load_dwordx4 %0, %6, off sc1\n\t"
      "global_load_dwordx4 %1, %7, off sc1\n\t"
      "global_load_dwordx4 %2, %8, off sc1\n\t"
      "global_load_dwordx4 %3, %9, off sc1\n\t"
      "global_load_dwordx4 %4, %10, off sc1\n\t"
      "global_load_dwordx4 %5, %11, off sc1\n\t"
      "s_waitcnt vmcnt(0)"
      : "=&v"(a), "=&v"(b), "=&v"(c), "=&v"(d), "=&v"(e), "=&v"(f)
      : "v"(pa), "v"(pb), "v"(pc), "v"(pd), "v"(pe), "v"(pf) : "memory");
}
__device__ __forceinline__ void ld8s_sc1(
    float& a0,float& a1,float& a2,float& a3,float& a4,float& a5,float& a6,float& a7,
    const float* p0,const float* p1,const float* p2,const float* p3,
    const float* p4,const float* p5,const float* p6,const float* p7) {
  asm volatile(
      "global_load_dword %0, %8, off sc1\n\t"
      "global_load_dword %1, %9, off sc1\n\t"
      "global_load_dword %2, %10, off sc1\n\t"
      "global_load_dword %3, %11, off sc1\n\t"
      "global_load_dword %4, %12, off sc1\n\t"
      "global_load_dword %5, %13, off sc1\n\t"
      "global_load_dword %6, %14, off sc1\n\t"
      "global_load_dword %7, %15, off sc1\n\t"
      "s_waitcnt vmcnt(0)"
      : "=&v"(a0),"=&v"(a1),"=&v"(a2),"=&v"(a3),
        "=&v"(a4),"=&v"(a5),"=&v"(a6),"=&v"(a7)
      : "v"(p0),"v"(p1),"v"(p2),"v"(p3),"v"(p4),"v"(p5),"v"(p6),"v"(p7)
      : "memory");
}

// acc_bs.(g) += xv.(bs) * wv.(g)
#define FMA16(a0,a1,a2,a3,xv,wv) \
  a0.x += xv.x*wv.x; a0.y += xv.x*wv.y; a0.z += xv.x*wv.z; a0.w += xv.x*wv.w; \
  a1.x += xv.y*wv.x; a1.y += xv.y*wv.y; a1.z += xv.y*wv.z; a1.w += xv.y*wv.w; \
  a2.x += xv.z*wv.x; a2.y += xv.z*wv.y; a2.z += xv.z*wv.z; a2.w += xv.z*wv.w; \
  a3.x += xv.w*wv.x; a3.y += xv.w*wv.y; a3.z += xv.w*wv.z; a3.w += xv.w*wv.w;

// Fence-free 16-block group barrier (monotonic counter, relaxed agent atomics).
__device__ __forceinline__ void group_barrier(unsigned* bar, unsigned& n) {
  n += 16;
  asm volatile("s_waitcnt vmcnt(0)" ::: "memory");
  __syncthreads();
  if (threadIdx.x == 0) {
    __hip_atomic_fetch_add(bar, 1u, __ATOMIC_RELAXED, __HIP_MEMORY_SCOPE_AGENT);
    unsigned cur;
    do {
      cur = __hip_atomic_load(bar, __ATOMIC_RELAXED, __HIP_MEMORY_SCOPE_AGENT);
    } while (cur < n);
  }
  __syncthreads();
}

__global__ void darnn_init(float* __restrict__ ws, float* __restrict__ out) {
  unsigned i = blockIdx.x * 256u + threadIdx.x;
  const unsigned span = WS_END - OFF_HE;
  for (unsigned idx = i; idx < span; idx += gridDim.x * 256u) ws[OFF_HE + idx] = 0.f;
  if (i < 256u) out[i] = 0.f;
}

__global__ __launch_bounds__(256, 1) void darnn_main(
    const float* __restrict__ in,   const float* __restrict__ WUe,   const float* __restrict__ ve,
    const float* __restrict__ Wih_e,const float* __restrict__ Whh_e,
    const float* __restrict__ bih_e,const float* __restrict__ bhh_e,
    const float* __restrict__ WUd,  const float* __restrict__ vd,
    const float* __restrict__ wbt,  const float* __restrict__ Wih_d,
    const float* __restrict__ Whh_d,const float* __restrict__ bih_d, const float* __restrict__ bhh_d,
    const float* __restrict__ WbW,  const float* __restrict__ Wbb,
    const float* __restrict__ vbW,  const float* __restrict__ vbb,
    float* __restrict__ ws, float* __restrict__ out)
{
  extern __shared__ __align__(16) float sm[];
  float* SLAB = sm;            // persistent weight slab
  float* SCR  = sm + SLAB_F;   // per-phase scratch
  const int tid = threadIdx.x;
  const int bid = blockIdx.x;
  const int grp = bid >> 4;
  const int mt  = bid & 15;
  const int b0  = grp << 4;

  float* XWt  = ws + OFF_XWT;
  float* XeWt = ws + OFF_XEWT;
  float* Xe   = ws + OFF_XE;
  unsigned* barp = (unsigned*)(ws + OFF_BAR) + grp * 32;
  unsigned barn = 0;

  // ---------------- P1: XWt[b][j][n] = sum_k X[b][k][n] * WU_e[j][512+k], b = bid
  {
    float* Xs = SCR;  // [128][68]
    const float* Xb = in + bid * 8256;
    for (int it = 0; it < 32; ++it) {
      int lin = tid + it * 256;
      int k = lin >> 7, n = lin & 127;
      Xs[n * 68 + k] = Xb[k * 129 + n];
    }
    __syncthreads();
    int j = tid & 63, nh = tid >> 6;
    float acc[32];
#pragma unroll
    for (int i = 0; i < 32; ++i) acc[i] = 0.f;
    const float* wrow = WUe + j * 576 + 512;
    for (int kc = 0; kc < 4; ++kc) {
      float4 w0 = *(const float4*)(wrow + kc * 16 + 0);
      float4 w1 = *(const float4*)(wrow + kc * 16 + 4);
      float4 w2 = *(const float4*)(wrow + kc * 16 + 8);
      float4 w3 = *(const float4*)(wrow + kc * 16 + 12);
#pragma unroll
      for (int ni = 0; ni < 32; ++ni) {
        const float* xp = Xs + (nh * 32 + ni) * 68 + kc * 16;
        float4 x0 = *(const float4*)(xp + 0);
        float4 x1 = *(const float4*)(xp + 4);
        float4 x2 = *(const float4*)(xp + 8);
        float4 x3 = *(const float4*)(xp + 12);
        acc[ni] += dot4(x0, w0) + dot4(x1, w1) + dot4(x2, w2) + dot4(x3, w3);
      }
    }
    float* dst = XWt + bid * 8192 + j * 128 + nh * 32;
#pragma unroll
    for (int ni = 0; ni < 32; ++ni) dst[ni] = acc[ni];
    __syncthreads();
  }

  // ---- load encoder weight slab once: SLAB[k*64 + r], r = ml*4 + gate
  {
    int r = tid & 63, kq = tid >> 6;
    int grow = (r & 3) * 256 + mt * 16 + (r >> 2);
#pragma unroll 4
    for (int q = 0; q < 24; ++q) {
      int k = kq * 96 + q * 4;
      float4 wv = (k < 128) ? *(const float4*)(Wih_e + grow * 128 + k)
                            : *(const float4*)(Whh_e + grow * 256 + (k - 128));
      SLAB[(k + 0) * 64 + r] = wv.x; SLAB[(k + 1) * 64 + r] = wv.y;
      SLAB[(k + 2) * 64 + r] = wv.z; SLAB[(k + 3) * 64 + r] = wv.w;
    }
  }

  // ================ ENCODER: 64 steps ================
  for (int t = 0; t < 64; ++t) {
    const int rd = t & 1, wr2 = (t + 1) & 1;
    // ---- EA: input attention for b = bid
    {
      float* Sj  = SCR;          // [64]
      float* Ssc = SCR + 64;     // [16][64]
      float* Eh  = SCR + 1088;   // [2][128]
      float* r8  = SCR + 1344;   // [8]
      {
        int p = tid >> 4, j4 = (tid & 15) << 2;
        float4 sv;
        ld1q_sc1(sv, ws + OFF_SP + (unsigned)(p * 256 + bid) * 64 + j4);
        *(float4*)(Ssc + p * 64 + j4) = sv;
      }
      __syncthreads();
      if (tid < 64) {
        float s = 0.f;
#pragma unroll
        for (int p = 0; p < 16; ++p) s += Ssc[p * 64 + tid];
        Sj[tid] = s;
      }
      __syncthreads();
      {
        int n = tid & 127, jh = tid >> 7;
        const float* xwp = XWt + bid * 8192 + n;
        float e = 0.f;
#pragma unroll
        for (int jj = 0; jj < 32; ++jj) {
          int j = (jh << 5) + jj;
          e += ve[j] * fast_tanh(xwp[j << 7] + Sj[j]);
        }
        Eh[(jh << 7) + n] = e;
      }
      __syncthreads();
      int lane = tid & 63, wid = tid >> 6;
      float En = (tid < 128) ? (Eh[tid] + Eh[128 + tid]) : -1e30f;
      float mx = wave_max(En);
      if (lane == 0) r8[wid] = mx;
      __syncthreads();
      mx = fmaxf(fmaxf(r8[0], r8[1]), fmaxf(r8[2], r8[3]));
      float ex = (tid < 128) ? __expf(En - mx) : 0.f;
      float sw = wave_sum(ex);
      if (lane == 0) r8[4 + wid] = sw;
      __syncthreads();
      float tot = r8[4] + r8[5] + r8[6] + r8[7];
      if (tid < 128)
        st1_sc1(ws + OFF_XA + bid * 128 + tid,
                in[bid * 8256 + t * 129 + tid] * (ex / tot));
    }
    group_barrier(barp, barn);

    // ---- EB: gates GEMM (K=384, weights LDS-resident) + pointwise + S_part
    {
      float* xah = SCR;            // [384][20]
      float* red = SCR + 7680;     // [256][16]
      float* hcs = SCR + 11776;    // [16][32]
      {
        float4 qv[6]; const float* ps[6]; int kk6[6], bb6[6];
#pragma unroll
        for (int i = 0; i < 2; ++i) {
          int idx = (tid + i * 256) * 4;
          bb6[i] = idx >> 7; kk6[i] = idx & 127;
          ps[i] = ws + OFF_XA + (unsigned)(b0 + bb6[i]) * 128 + kk6[i];
        }
#pragma unroll
        for (int i = 0; i < 4; ++i) {
          int idx = (tid + i * 256) * 4;
          int bl = idx >> 8, k = idx & 255;
          bb6[2 + i] = bl; kk6[2 + i] = 128 + k;
          ps[2 + i] = ws + OFF_HE + (unsigned)rd * 65536 + (unsigned)(b0 + bl) * 256 + k;
        }
        ld6q_sc1(qv[0], qv[1], qv[2], qv[3], qv[4], qv[5],
                 ps[0], ps[1], ps[2], ps[3], ps[4], ps[5]);
#pragma unroll
        for (int i = 0; i < 6; ++i) {
          xah[(kk6[i] + 0) * 20 + bb6[i]] = qv[i].x;
          xah[(kk6[i] + 1) * 20 + bb6[i]] = qv[i].y;
          xah[(kk6[i] + 2) * 20 + bb6[i]] = qv[i].z;
          xah[(kk6[i] + 3) * 20 + bb6[i]] = qv[i].w;
        }
      }
      __syncthreads();
      const int ks = tid >> 6, ml = (tid >> 2) & 15, b4 = tid & 3;
      float4 a0 = {0,0,0,0}, a1 = {0,0,0,0}, a2 = {0,0,0,0}, a3 = {0,0,0,0};
      {
        const float* xp = xah + (unsigned)(ks * 96) * 20 + b4 * 4;
        const float* wp = SLAB + (unsigned)(ks * 96) * 64 + ml * 4;
#pragma unroll 8
        for (int kk = 0; kk < 96; ++kk) {
          float4 xv = *(const float4*)(xp + kk * 20);
          float4 wv = *(const float4*)(wp + kk * 64);
          FMA16(a0, a1, a2, a3, xv, wv);
        }
      }
      {
        int tIdx = ml * 4 + b4;
        float* rp = red + (unsigned)(ks * 64 + tIdx) * 16;
        *(float4*)(rp + 0) = a0; *(float4*)(rp + 4) = a1;
        *(float4*)(rp + 8) = a2; *(float4*)(rp + 12) = a3;
      }
      __syncthreads();
      {
        int bl = tid & 15, m2 = tid >> 4;
        int t2 = m2 * 4 + (bl >> 2), bs = bl & 3;
        float4 gate = {0,0,0,0};
#pragma unroll
        for (int k2 = 0; k2 < 4; ++k2) {
          float4 rr = *(const float4*)(red + (unsigned)(k2 * 64 + t2) * 16 + bs * 4);
          gate.x += rr.x; gate.y += rr.y; gate.z += rr.z; gate.w += rr.w;
        }
        int m = mt * 16 + m2;
        float gi = gate.x + bih_e[m]       + bhh_e[m];
        float gf = gate.y + bih_e[256 + m] + bhh_e[256 + m];
        float gg = gate.z + bih_e[512 + m] + bhh_e[512 + m];
        float go = gate.w + bih_e[768 + m] + bhh_e[768 + m];
        unsigned bi = (unsigned)(b0 + bl) * 256 + m;
        float co = ws[OFF_CE + (unsigned)rd * 65536 + bi];
        float cn = fast_sig(gf) * co + fast_sig(gi) * fast_tanh(gg);
        float hn = fast_sig(go) * fast_tanh(cn);
        st1_sc1(ws + OFF_HE + (unsigned)wr2 * 65536 + bi, hn);
        ws[OFF_CE + (unsigned)wr2 * 65536 + bi] = cn;
        st1_sc1(Xe + ((unsigned)(b0 + bl) * 64 + t) * 256 + m, hn);
        hcs[bl * 32 + m2] = hn;
        hcs[bl * 32 + 16 + m2] = cn;
      }
      __syncthreads();
      {  // S_part[mt][b][j]
        int j = tid & 63, wq = tid >> 6;
        const float* wre = WUe + j * 576 + mt * 16;
        float4 wh[4], wc[4];
#pragma unroll
        for (int q = 0; q < 4; ++q) {
          wh[q] = *(const float4*)(wre + q * 4);
          wc[q] = *(const float4*)(wre + 256 + q * 4);
        }
#pragma unroll
        for (int bs2 = 0; bs2 < 4; ++bs2) {
          int bl2 = wq * 4 + bs2;
          const float* hp = hcs + bl2 * 32;
          float s = 0.f;
#pragma unroll
          for (int q = 0; q < 4; ++q) {
            float4 hv = *(const float4*)(hp + q * 4);
            float4 cv = *(const float4*)(hp + 16 + q * 4);
            s += dot4(hv, wh[q]) + dot4(cv, wc[q]);
          }
          st1_sc1(ws + OFF_SP + (unsigned)(mt * 256 + b0 + bl2) * 64 + j, s);
        }
      }
    }
    group_barrier(barp, barn);
  }

  // ---- fill Xe row into registers: xe[t] = Xe[bid][t][tid]  (sc1, one time)
  float xe[64];
  {
    const float* xb = Xe + (unsigned)bid * 16384 + tid;
#pragma unroll
    for (int g8 = 0; g8 < 8; ++g8) {
      ld8s_sc1(xe[g8*8+0], xe[g8*8+1], xe[g8*8+2], xe[g8*8+3],
               xe[g8*8+4], xe[g8*8+5], xe[g8*8+6], xe[g8*8+7],
               xb + (g8*8+0)*256, xb + (g8*8+1)*256, xb + (g8*8+2)*256,
               xb + (g8*8+3)*256, xb + (g8*8+4)*256, xb + (g8*8+5)*256,
               xb + (g8*8+6)*256, xb + (g8*8+7)*256);
    }
  }

  // ---- load decoder weight slab once: SLAB[k*64 + r], k < 256
  {
    int r = tid & 63, kq = tid >> 6;
    int grow = (r & 3) * 256 + mt * 16 + (r >> 2);
#pragma unroll 4
    for (int q = 0; q < 16; ++q) {
      int k = kq * 64 + q * 4;
      float4 wv = *(const float4*)(Whh_d + grow * 256 + k);
      SLAB[(k + 0) * 64 + r] = wv.x; SLAB[(k + 1) * 64 + r] = wv.y;
      SLAB[(k + 2) * 64 + r] = wv.z; SLAB[(k + 3) * 64 + r] = wv.w;
    }
  }

  // ---------------- P2: XeWt[b][j][t'] = sum_k Xe[b][t'][k] * WU_d[j][512+k]
  {
    float* XeT = SCR;          // [64][68]
    float* Wdc = SCR + 4352;   // [64][68]
    int tt2 = tid & 15, jq = tid >> 4;
    for (int jc = 0; jc < 4; ++jc) {
      float4 c0 = {0,0,0,0}, c1 = {0,0,0,0}, c2 = {0,0,0,0}, c3 = {0,0,0,0};
      for (int kc = 0; kc < 4; ++kc) {
        __syncthreads();
        if ((tid >> 6) == kc) {
          int kk = tid & 63;
#pragma unroll
          for (int t4 = 0; t4 < 16; ++t4) {
            float4 v = { xe[t4*4+0], xe[t4*4+1], xe[t4*4+2], xe[t4*4+3] };
            *(float4*)(XeT + kk * 68 + t4 * 4) = v;
          }
        }
#pragma unroll
        for (int it = 0; it < 4; ++it) {
          int lin = tid + it * 256;
          int jj = lin >> 4, k4 = (lin & 15) * 4;
          float4 wv = *(const float4*)(WUd + (unsigned)(jc * 64 + jj) * 768 + 512 + kc * 64 + k4);
          Wdc[(k4 + 0) * 68 + jj] = wv.x; Wdc[(k4 + 1) * 68 + jj] = wv.y;
          Wdc[(k4 + 2) * 68 + jj] = wv.z; Wdc[(k4 + 3) * 68 + jj] = wv.w;
        }
        __syncthreads();
#pragma unroll 8
        for (int kk = 0; kk < 64; ++kk) {
          float4 xv = *(const float4*)(XeT + kk * 68 + tt2 * 4);
          float4 wv = *(const float4*)(Wdc + kk * 68 + jq * 4);
          FMA16(c0, c1, c2, c3, wv, xv);
        }
      }
      {
        int jb = jc * 64 + jq * 4;
        *(float4*)(XeWt + ((unsigned)bid * 256 + jb + 0) * 64 + tt2 * 4) = c0;
        *(float4*)(XeWt + ((unsigned)bid * 256 + jb + 1) * 64 + tt2 * 4) = c1;
        *(float4*)(XeWt + ((unsigned)bid * 256 + jb + 2) * 64 + tt2 * 4) = c2;
        *(float4*)(XeWt + ((unsigned)bid * 256 + jb + 3) * 64 + tt2 * 4) = c3;
      }
    }
    __syncthreads();
  }

  // ================ DECODER: 63 steps ================
  for (int t = 0; t < 63; ++t) {
    const int rd = t & 1, wr2 = (t + 1) & 1;
    // ---- DA: temporal attention + ctx + y_tilde for b = bid
    {
      float* Sdj  = SCR;        // [256]
      float* lp   = SCR + 256;  // [4][64]
      float* beta = SCR + 512;  // [64]
      float* r8   = SCR + 576;  // [8]
      float* Ssd  = SCR + 640;  // [16][256]
      {
        float4 qv[4]; const float* ps[4]; int pp[4], jj[4];
#pragma unroll
        for (int i = 0; i < 4; ++i) {
          int idx = (tid + i * 256) * 4;
          pp[i] = idx >> 8; jj[i] = idx & 255;
          ps[i] = ws + OFF_SDP + (unsigned)(pp[i] * 256 + bid) * 256 + jj[i];
        }
        ld4q_sc1(qv[0], qv[1], qv[2], qv[3], ps[0], ps[1], ps[2], ps[3]);
#pragma unroll
        for (int i = 0; i < 4; ++i) *(float4*)(Ssd + pp[i] * 256 + jj[i]) = qv[i];
      }
      __syncthreads();
      {
        float s = 0.f;
#pragma unroll
        for (int p = 0; p < 16; ++p) s += Ssd[p * 256 + tid];
        Sdj[tid] = s;
      }
      __syncthreads();
      {
        int tq = tid & 63, q = tid >> 6;
        const float* xew = XeWt + (unsigned)bid * 16384 + tq;
        float l = 0.f;
#pragma unroll 8
        for (int jj2 = 0; jj2 < 64; ++jj2) {
          int j = q * 64 + jj2;
          l += vd[j] * fast_tanh(xew[j << 6] + Sdj[j]);
        }
        lp[q * 64 + tq] = l;
      }
      __syncthreads();
      if (tid < 64) {
        float lv = lp[tid] + lp[64 + tid] + lp[128 + tid] + lp[192 + tid];
        float mx = wave_max(lv);
        float ex = __expf(lv - mx);
        float sw = wave_sum(ex);
        beta[tid] = ex / sw;
      }
      __syncthreads();
      {
        float acc = 0.f;
#pragma unroll
        for (int tt3 = 0; tt3 < 64; ++tt3) acc += beta[tt3] * xe[tt3];
        st1_sc1(ws + OFF_CTX + (unsigned)bid * 256 + tid, acc);
        float yp = acc * wbt[1 + tid];
        float swv = wave_sum(yp);
        if ((tid & 63) == 0) r8[tid >> 6] = swv;
      }
      __syncthreads();
      if (tid == 0) {
        float yt = wbt[0] * in[bid * 8256 + t * 129 + 128] + r8[0] + r8[1] + r8[2] + r8[3];
        st1_sc1(ws + OFF_YT + bid, yt);
      }
    }
    group_barrier(barp, barn);

    // ---- DB: decoder gates GEMM (K=256, weights LDS-resident) + pointwise + Sd_part
    {
      float* hT  = SCR;            // [256][20]
      float* red = SCR + 5120;     // [256][16]
      float* hcs = SCR + 9216;     // [16][32]
      float* yts = SCR + 9728;     // [16]
      {
        float4 qv[4]; const float* ps[4]; int kk4[4], bb4[4];
#pragma unroll
        for (int i = 0; i < 4; ++i) {
          int idx = (tid + i * 256) * 4;
          bb4[i] = idx >> 8; kk4[i] = idx & 255;
          ps[i] = ws + OFF_HD + (unsigned)rd * 65536 + (unsigned)(b0 + bb4[i]) * 256 + kk4[i];
        }
        ld4q_sc1(qv[0], qv[1], qv[2], qv[3], ps[0], ps[1], ps[2], ps[3]);
#pragma unroll
        for (int i = 0; i < 4; ++i) {
          hT[(kk4[i] + 0) * 20 + bb4[i]] = qv[i].x;
          hT[(kk4[i] + 1) * 20 + bb4[i]] = qv[i].y;
          hT[(kk4[i] + 2) * 20 + bb4[i]] = qv[i].z;
          hT[(kk4[i] + 3) * 20 + bb4[i]] = qv[i].w;
        }
        if (tid < 16) yts[tid] = ld1_sc1(ws + OFF_YT + b0 + tid);
      }
      __syncthreads();
      const int ks = tid >> 6, ml = (tid >> 2) & 15, b4 = tid & 3;
      float4 a0 = {0,0,0,0}, a1 = {0,0,0,0}, a2 = {0,0,0,0}, a3 = {0,0,0,0};
      {
        const float* xp = hT + (unsigned)(ks * 64) * 20 + b4 * 4;
        const float* wp = SLAB + (unsigned)(ks * 64) * 64 + ml * 4;
#pragma unroll 8
        for (int kk = 0; kk < 64; ++kk) {
          float4 xv = *(const float4*)(xp + kk * 20);
          float4 wv = *(const float4*)(wp + kk * 64);
          FMA16(a0, a1, a2, a3, xv, wv);
        }
      }
      {
        int tIdx = ml * 4 + b4;
        float* rp = red + (unsigned)(ks * 64 + tIdx) * 16;
        *(float4*)(rp + 0) = a0; *(float4*)(rp + 4) = a1;
        *(float4*)(rp + 8) = a2; *(float4*)(rp + 12) = a3;
      }
      __syncthreads();
      {
        int bl = tid & 15, m2 = tid >> 4;
        int t2 = m2 * 4 + (bl >> 2), bs = bl & 3;
        float4 gate = {0,0,0,0};
#pragma unroll
        for (int k2 = 0; k2 < 4; ++k2) {
          float4 rr = *(const float4*)(red + (unsigned)(k2 * 64 + t2) * 16 + bs * 4);
          gate.x += rr.x; gate.y += rr.y; gate.z += rr.z; gate.w += rr.w;
        }
        int m = mt * 16 + m2;
        float yt = yts[bl];
        float gi = gate.x + yt * Wih_d[m]       + bih_d[m]       + bhh_d[m];
        float gf = gate.y + yt * Wih_d[256 + m] + bih_d[256 + m] + bhh_d[256 + m];
        float gg = gate.z + yt * Wih_d[512 + m] + bih_d[512 + m] + bhh_d[512 + m];
        float go = gate.w + yt * Wih_d[768 + m] + bih_d[768 + m] + bhh_d[768 + m];
        unsigned bi = (unsigned)(b0 + bl) * 256 + m;
        float co = ws[OFF_CD + (unsigned)rd * 65536 + bi];
        float cn = fast_sig(gf) * co + fast_sig(gi) * fast_tanh(gg);
        float hn = fast_sig(go) * fast_tanh(cn);
        st1_sc1(ws + OFF_HD + (unsigned)wr2 * 65536 + bi, hn);
        ws[OFF_CD + (unsigned)wr2 * 65536 + bi] = cn;
        hcs[bl * 32 + m2] = hn;
        hcs[bl * 32 + 16 + m2] = cn;
      }
      __syncthreads();
      {  // Sd_part[mt][b][j], j = tid
        int j = tid;
        const float* wrd = WUd + (unsigned)j * 768 + mt * 16;
        float4 wh[4], wc[4];
#pragma unroll
        for (int q = 0; q < 4; ++q) {
          wh[q] = *(const float4*)(wrd + q * 4);
          wc[q] = *(const float4*)(wrd + 256 + q * 4);
        }
#pragma unroll 4
        for (int bl2 = 0; bl2 < 16; ++bl2) {
          const float* hp = hcs + bl2 * 32;
          float s = 0.f;
#pragma unroll
          for (int q = 0; q < 4; ++q) {
            float4 hv = *(const float4*)(hp + q * 4);
            float4 cv = *(const float4*)(hp + 16 + q * 4);
            s += dot4(hv, wh[q]) + dot4(cv, wc[q]);
          }
          st1_sc1(ws + OFF_SDP + (unsigned)(mt * 256 + b0 + bl2) * 256 + j, s);
        }
      }
    }
    group_barrier(barp, barn);
  }

  // ---------------- FINAL
  {
    float* hsf  = SCR;          // [16][516]
    float* hidw = SCR + 8256;   // [16][17]
    for (int half = 0; half < 2; ++half) {
      float4 qv[4]; const float* ps[4]; int kk[4], bb[4];
#pragma unroll
      for (int i = 0; i < 4; ++i) {
        int idx = (tid + (half * 4 + i) * 256) * 4;
        bb[i] = idx >> 9; int k = idx & 511; kk[i] = k;
        ps[i] = (k < 256)
            ? ws + OFF_HD + 65536u + (unsigned)(b0 + bb[i]) * 256 + k
            : ws + OFF_CTX + (unsigned)(b0 + bb[i]) * 256 + (k - 256);
      }
      ld4q_sc1(qv[0], qv[1], qv[2], qv[3], ps[0], ps[1], ps[2], ps[3]);
#pragma unroll
      for (int i = 0; i < 4; ++i) *(float4*)(hsf + bb[i] * 516 + kk[i]) = qv[i];
    }
    __syncthreads();
    int bl = tid & 15, p4 = tid >> 4;
    int row = mt * 16 + p4;
    const float* wrow = WbW + (unsigned)row * 512;
    const float* hp = hsf + bl * 516;
    float acc = Wbb[row];
#pragma unroll 8
    for (int q = 0; q < 128; ++q) {
      float4 hv = *(const float4*)(hp + q * 4);
      float4 wv = *(const float4*)(wrow + q * 4);
      acc += dot4(hv, wv);
    }
    hidw[bl * 17 + p4] = acc * vbW[row];
    __syncthreads();
    if (tid < 16) {
      float s = 0.f;
#pragma unroll
      for (int p = 0; p < 16; ++p) s += hidw[tid * 17 + p];
      if (mt == 0) s += vbb[0];
      atomicAdd(&out[b0 + tid], s);
    }
  }
}

extern "C" void kernel_launch(void* const* d_in, const int* in_sizes, int n_in,
                              void* d_out, int out_size, void* d_ws, size_t ws_size,
                              hipStream_t stream) {
  (void)in_sizes; (void)n_in; (void)out_size; (void)ws_size;
  const float* in    = (const float*)d_in[0];
  const float* WUe   = (const float*)d_in[1];
  const float* ve    = (const float*)d_in[2];
  const float* Wih_e = (const float*)d_in[3];
  const float* Whh_e = (const float*)d_in[4];
  const float* bih_e = (const float*)d_in[5];
  const float* bhh_e = (const float*)d_in[6];
  const float* WUd   = (const float*)d_in[7];
  const float* vd    = (const float*)d_in[8];
  const float* wbt   = (const float*)d_in[9];
  const float* Wih_d = (const float*)d_in[10];
  const float* Whh_d = (const float*)d_in[11];
  const float* bih_d = (const float*)d_in[12];
  const float* bhh_d = (const float*)d_in[13];
  const float* WbW   = (const float*)d_in[14];
  const float* Wbb   = (const float*)d_in[15];
  const float* vbW   = (const float*)d_in[16];
  const float* vbb   = (const float*)d_in[17];
  float* ws  = (float*)d_ws;
  float* out = (float*)d_out;

  hipFuncSetAttribute((const void*)darnn_main,
                      hipFuncAttributeMaxDynamicSharedMemorySize, SMEM_BYTES);
  hipLaunchKernelGGL(darnn_init, dim3(1024), dim3(256), 0, stream, ws, out);
  hipLaunchKernelGGL(darnn_main, dim3(256), dim3(256), SMEM_BYTES, stream,
                     in, WUe, ve, Wih_e, Whh_e, bih_e, bhh_e,
                     WUd, vd, wbt, Wih_d, Whh_d, bih_d, bhh_d,
                     WbW, Wbb, vbW, vbb, ws, out);
}

// Round 5
// 1497.915 us; speedup vs baseline: 10.6971x; 1.4764x over previous
//
#include <hip/hip_runtime.h>
#include <math.h>

// Problem dims: B=256, T=64, N=128, M=256, P=256, YD=1
// 256 blocks x 512 threads (8 waves). Group = 16 blocks = 16 batches; block role mt = m-tile.

// Workspace layout (float offsets)
#define OFF_XWT   0u          // [256][64][128]  XWt[b][j][n]   (block-local)
#define OFF_XEWT  2097152u    // [256][256][64]  XeWt[b][j][t'] (block-local)
#define OFF_XE    6291456u    // [256][64][256]  Xe[b][t][m]    (sc1 w, sc1 r once)
#define OFF_HE    10485760u   // [2][256][256]   h_e            (sc1 w/r)
#define OFF_HD    10616832u   // [2][256][256]   h_d            (sc1 w/r)
#define OFF_SB    10747904u   // [2][256][64]    S accum        (atomic add / sc1 r+zero)
#define OFF_SDB   10780672u   // [2][256][256]   Sd accum       (atomic add / sc1 r+zero)
#define OFF_XA    10911744u   // [256][128]      x*alpha        (sc1 w/r)
#define OFF_CTX   10944512u   // [256][256]      ctx            (sc1 w/r)
#define OFF_YT    11010048u   // [256]           y_tilde        (sc1 w/r)
#define OFF_BAR   11010304u   // 16 groups x 32 u32
#define WS_END    11010816u

// LDS (floats): SLAB (weights, persistent) | PER (small persistent) | SCR (per-phase)
#define SLAB_F 24576
#define PER_F  2432
#define SCR_F  12288
#define SMEM_F (SLAB_F + PER_F + SCR_F)
#define SMEM_BYTES (SMEM_F * 4)   // 157184 B <= 160 KB

__device__ __forceinline__ float fast_tanh(float x) {
  float xc = fminf(15.f, fmaxf(-15.f, x));
  float e = __expf(2.f * xc);
  return 1.f - 2.f * __builtin_amdgcn_rcpf(e + 1.f);
}
__device__ __forceinline__ float fast_sig(float x) {
  float xc = fminf(30.f, fmaxf(-30.f, x));
  return __builtin_amdgcn_rcpf(1.f + __expf(-xc));
}
__device__ __forceinline__ float wave_max(float v) {
#pragma unroll
  for (int o = 32; o; o >>= 1) v = fmaxf(v, __shfl_xor(v, o));
  return v;
}
__device__ __forceinline__ float wave_sum(float v) {
#pragma unroll
  for (int o = 32; o; o >>= 1) v += __shfl_xor(v, o);
  return v;
}
__device__ __forceinline__ float dot4(float4 a, float4 b) {
  return a.x*b.x + a.y*b.y + a.z*b.z + a.w*b.w;
}

// ---- device-scope (sc1) coherent helpers ----
// NOTE: float4 is allowed only as an ASM OUTPUT ("=&v"); struct inputs in "v"
// constraints do not compile on gfx950 ("indirect register inputs").
__device__ __forceinline__ void st1_sc1(float* p, float v) {
  asm volatile("global_store_dword %0, %1, off sc1" :: "v"(p), "v"(v) : "memory");
}
__device__ __forceinline__ void ld1q_sc1(float4& a, const float* pa) {
  asm volatile("global_load_dwordx4 %0, %1, off sc1\n\ts_waitcnt vmcnt(0)"
               : "=&v"(a) : "v"(pa) : "memory");
}
__device__ __forceinline__ void ld3q_sc1(float4& a, float4& b, float4& c,
    const float* pa, const float* pb, const float* pc) {
  asm volatile(
      "global_load_dwordx4 %0, %3, off sc1\n\t"
      "global_load_dwordx4 %1, %4, off sc1\n\t"
      "global_load_dwordx4 %2, %5, off sc1\n\t"
      "s_waitcnt vmcnt(0)"
      : "=&v"(a), "=&v"(b), "=&v"(c)
      : "v"(pa), "v"(pb), "v"(pc) : "memory");
}
__device__ __forceinline__ void ld4q_sc1(float4& a, float4& b, float4& c, float4& d,
    const float* pa, const float* pb, const float* pc, const float* pd) {
  asm volatile(
      "global_load_dwordx4 %0, %4, off sc1\n\t"
      "global_load_dwordx4 %1, %5, off sc1\n\t"
      "global_load_dwordx4 %2, %6, off sc1\n\t"
      "global_load_dwordx4 %3, %7, off sc1\n\t"
      "s_waitcnt vmcnt(0)"
      : "=&v"(a), "=&v"(b), "=&v"(c), "=&v"(d)
      : "v"(pa), "v"(pb), "v"(pc), "v"(pd) : "memory");
}
__device__ __forceinline__ void ld2q1s_sc1(float4& a, float4& b, float& s,
    const float* pa, const float* pb, const float* ps) {
  asm volatile(
      "global_load_dwordx4 %0, %3, off sc1\n\t"
      "global_load_dwordx4 %1, %4, off sc1\n\t"
      "global_load_dword %2, %5, off sc1\n\t"
      "s_waitcnt vmcnt(0)"
      : "=&v"(a), "=&v"(b), "=&v"(s)
      : "v"(pa), "v"(pb), "v"(ps) : "memory");
}
__device__ __forceinline__ void ld8s_sc1(
    float& a0,float& a1,float& a2,float& a3,float& a4,float& a5,float& a6,float& a7,
    const float* p0,const float* p1,const float* p2,const float* p3,
    const float* p4,const float* p5,const float* p6,const float* p7) {
  asm volatile(
      "global_load_dword %0, %8, off sc1\n\t"
      "global_load_dword %1, %9, off sc1\n\t"
      "global_load_dword %2, %10, off sc1\n\t"
      "global_load_dword %3, %11, off sc1\n\t"
      "global_load_dword %4, %12, off sc1\n\t"
      "global_load_dword %5, %13, off sc1\n\t"
      "global_load_dword %6, %14, off sc1\n\t"
      "global_load_dword %7, %15, off sc1\n\t"
      "s_waitcnt vmcnt(0)"
      : "=&v"(a0),"=&v"(a1),"=&v"(a2),"=&v"(a3),
        "=&v"(a4),"=&v"(a5),"=&v"(a6),"=&v"(a7)
      : "v"(p0),"v"(p1),"v"(p2),"v"(p3),"v"(p4),"v"(p5),"v"(p6),"v"(p7)
      : "memory");
}
__device__ __forceinline__ void atomic_add_sc1(float* p, float v) {
  asm volatile("global_atomic_add_f32 %0, %1, off sc1" :: "v"(p), "v"(v) : "memory");
}

#define FMA16S(a0,a1,a2,a3,x0,x1,x2,x3,wv) \
  a0.x += x0*wv.x; a0.y += x0*wv.y; a0.z += x0*wv.z; a0.w += x0*wv.w; \
  a1.x += x1*wv.x; a1.y += x1*wv.y; a1.z += x1*wv.z; a1.w += x1*wv.w; \
  a2.x += x2*wv.x; a2.y += x2*wv.y; a2.z += x2*wv.z; a2.w += x2*wv.w; \
  a3.x += x3*wv.x; a3.y += x3*wv.y; a3.z += x3*wv.z; a3.w += x3*wv.w;

#define FMA16V(a0,a1,a2,a3,xv,wv) \
  a0.x += xv.x*wv.x; a0.y += xv.x*wv.y; a0.z += xv.x*wv.z; a0.w += xv.x*wv.w; \
  a1.x += xv.y*wv.x; a1.y += xv.y*wv.y; a1.z += xv.y*wv.z; a1.w += xv.y*wv.w; \
  a2.x += xv.z*wv.x; a2.y += xv.z*wv.y; a2.z += xv.z*wv.z; a2.w += xv.z*wv.w; \
  a3.x += xv.w*wv.x; a3.y += xv.w*wv.y; a3.z += xv.w*wv.z; a3.w += xv.w*wv.w;

// Fence-free 16-block group barrier (monotonic counter, relaxed agent atomics).
__device__ __forceinline__ void group_barrier(unsigned* bar, unsigned& n) {
  n += 16;
  asm volatile("s_waitcnt vmcnt(0)" ::: "memory");
  __syncthreads();
  if (threadIdx.x == 0) {
    __hip_atomic_fetch_add(bar, 1u, __ATOMIC_RELAXED, __HIP_MEMORY_SCOPE_AGENT);
    unsigned cur;
    do {
      cur = __hip_atomic_load(bar, __ATOMIC_RELAXED, __HIP_MEMORY_SCOPE_AGENT);
    } while (cur < n);
  }
  __syncthreads();
}

__global__ void darnn_init(float* __restrict__ ws, float* __restrict__ out) {
  unsigned i = blockIdx.x * 256u + threadIdx.x;
  const unsigned span = WS_END - OFF_HE;
  for (unsigned idx = i; idx < span; idx += gridDim.x * 256u) ws[OFF_HE + idx] = 0.f;
  if (i < 256u) out[i] = 0.f;
}

__global__ __launch_bounds__(512, 2) void darnn_main(
    const float* __restrict__ in,   const float* __restrict__ WUe,   const float* __restrict__ ve,
    const float* __restrict__ Wih_e,const float* __restrict__ Whh_e,
    const float* __restrict__ bih_e,const float* __restrict__ bhh_e,
    const float* __restrict__ WUd,  const float* __restrict__ vd,
    const float* __restrict__ wbt,  const float* __restrict__ Wih_d,
    const float* __restrict__ Whh_d,const float* __restrict__ bih_d, const float* __restrict__ bhh_d,
    const float* __restrict__ WbW,  const float* __restrict__ Wbb,
    const float* __restrict__ vbW,  const float* __restrict__ vbb,
    float* __restrict__ ws, float* __restrict__ out)
{
  extern __shared__ __align__(16) float sm[];
  float* SLAB = sm;
  float* PER  = sm + SLAB_F;
  float* SCR  = sm + SLAB_F + PER_F;
  const int tid = threadIdx.x;
  const int bid = blockIdx.x;
  const int grp = bid >> 4;
  const int mt  = bid & 15;
  const int b0  = grp << 4;

  float* XWt  = ws + OFF_XWT;
  float* XeWt = ws + OFF_XEWT;
  float* Xe   = ws + OFF_XE;
  unsigned* barp = (unsigned*)(ws + OFF_BAR) + grp * 32;
  unsigned barn = 0;

  // PER (encoder): wue_s [64][36] @0 (cols 0-15 = h-w, 16-31 = c-w); ve_s [64] @2304; bsum_e [64] @2368
  float* wue_s  = PER;
  float* ve_s   = PER + 2304;
  float* bsum_e = PER + 2368;

  // ---- one-time encoder staging ----
  {
    // encoder weight slab: SLAB[k*64 + r], r = ml*4 + gate, k < 384
    int r = tid & 63, kq = tid >> 6;
    int grow = (r & 3) * 256 + mt * 16 + (r >> 2);
#pragma unroll 4
    for (int q = 0; q < 12; ++q) {
      int k = kq * 48 + q * 4;
      float4 wv = (k < 128) ? *(const float4*)(Wih_e + grow * 128 + k)
                            : *(const float4*)(Whh_e + grow * 256 + (k - 128));
      SLAB[(k + 0) * 64 + r] = wv.x; SLAB[(k + 1) * 64 + r] = wv.y;
      SLAB[(k + 2) * 64 + r] = wv.z; SLAB[(k + 3) * 64 + r] = wv.w;
    }
    // wue_s
    {
      int lin = tid * 4;  // 2048
      int j = lin >> 5, c0 = lin & 31;
      int col = (c0 < 16) ? (mt * 16 + c0) : (256 + mt * 16 + (c0 - 16));
      float4 wv = *(const float4*)(WUe + j * 576 + col);
      *(float4*)(wue_s + j * 36 + c0) = wv;
    }
    if (tid < 64) {
      ve_s[tid] = ve[tid];
      int g = tid >> 4, m2 = tid & 15, m = mt * 16 + m2;
      bsum_e[tid] = bih_e[g * 256 + m] + bhh_e[g * 256 + m];
    }
  }

  // ---------------- P1: XWt[bid][j][n] = sum_k X[bid][k][n] * WU_e[j][512+k]
  {
    float* Xs = SCR;  // [128][68]
    const float* Xb = in + bid * 8256;
    __syncthreads();
    for (int it = 0; it < 16; ++it) {
      int lin = tid + it * 512;
      int k = lin >> 7, n = lin & 127;
      Xs[n * 68 + k] = Xb[k * 129 + n];
    }
    __syncthreads();
    int j = tid & 63, nh = tid >> 6;
    float acc[16];
#pragma unroll
    for (int i = 0; i < 16; ++i) acc[i] = 0.f;
    const float* wrow = WUe + j * 576 + 512;
    for (int kc = 0; kc < 4; ++kc) {
      float4 w0 = *(const float4*)(wrow + kc * 16 + 0);
      float4 w1 = *(const float4*)(wrow + kc * 16 + 4);
      float4 w2 = *(const float4*)(wrow + kc * 16 + 8);
      float4 w3 = *(const float4*)(wrow + kc * 16 + 12);
#pragma unroll
      for (int ni = 0; ni < 16; ++ni) {
        const float* xp = Xs + (nh * 16 + ni) * 68 + kc * 16;
        acc[ni] += dot4(*(const float4*)(xp + 0),  w0) + dot4(*(const float4*)(xp + 4),  w1)
                 + dot4(*(const float4*)(xp + 8),  w2) + dot4(*(const float4*)(xp + 12), w3);
      }
    }
    float* dst = XWt + bid * 8192 + j * 128 + nh * 16;
#pragma unroll
    for (int ni = 0; ni < 16; ++ni) dst[ni] = acc[ni];
    __syncthreads();
  }

  // hoist attention-weight row into regs (constant over t)
  float4 whc[8];
#pragma unroll
  for (int q = 0; q < 8; ++q) whc[q] = *(const float4*)(wue_s + (tid & 63) * 36 + q * 4);
  float4 bsE = {0,0,0,0};
  {
    int m2 = tid & 15;
    bsE.x = bsum_e[m2]; bsE.y = bsum_e[16 + m2];
    bsE.z = bsum_e[32 + m2]; bsE.w = bsum_e[48 + m2];
  }
  float c_reg = 0.f;   // c-state for thread (m2 = tid&15, bl = (tid>>4)&15), tid<256

  // ================ ENCODER: 64 steps ================
  for (int t = 0; t < 64; ++t) {
    const int rd = t & 1, wr2 = (t + 1) & 1;
    // ---- EA: input attention for b = bid
    {
      float* Sj = SCR;        // [64]
      float* Eh = SCR + 64;   // [4][128]
      float* r8 = SCR + 576;  // [8]
      if (tid < 16) {
        float* sp = ws + OFF_SB + (unsigned)rd * 16384 + (unsigned)bid * 64 + tid * 4;
        float4 sv;
        ld1q_sc1(sv, sp);
        st1_sc1(sp + 0, 0.f); st1_sc1(sp + 1, 0.f);
        st1_sc1(sp + 2, 0.f); st1_sc1(sp + 3, 0.f);
        *(float4*)(Sj + tid * 4) = sv;
      }
      __syncthreads();
      {
        int n = tid & 127, jh = tid >> 7;
        const float* xwp = XWt + bid * 8192 + n;
        float e = 0.f;
#pragma unroll
        for (int jj = 0; jj < 16; ++jj) {
          int j = jh * 16 + jj;
          e += ve_s[j] * fast_tanh(xwp[j << 7] + Sj[j]);
        }
        Eh[jh * 128 + n] = e;
      }
      __syncthreads();
      int lane = tid & 63, wid = tid >> 6;
      float En = (tid < 128) ? (Eh[tid] + Eh[128 + tid] + Eh[256 + tid] + Eh[384 + tid]) : -1e30f;
      float mx = wave_max(En);
      if (tid < 128 && lane == 0) r8[wid] = mx;
      __syncthreads();
      mx = fmaxf(r8[0], r8[1]);
      float ex = (tid < 128) ? __expf(En - mx) : 0.f;
      float sw = wave_sum(ex);
      if (tid < 128 && lane == 0) r8[4 + wid] = sw;
      __syncthreads();
      float tot = r8[4] + r8[5];
      if (tid < 128)
        st1_sc1(ws + OFF_XA + bid * 128 + tid,
                in[bid * 8256 + t * 129 + tid] * (ex / tot));
    }
    group_barrier(barp, barn);

    // ---- EB: gates GEMM (K=384) + pointwise + S atomics
    {
      float* xbk = SCR;            // [16][396]  (x|h per batch, conflict-free staging)
      float* red = SCR;            // [512][20]  alias after sync
      float* hcs = SCR + 10240;    // [16][32]
      {
        int i0 = tid * 4;            int bl0 = i0 >> 7, k0 = i0 & 127;
        int i1 = tid * 4;            int bl1 = i1 >> 8, k1 = i1 & 255;
        int i2 = (tid + 512) * 4;    int bl2 = i2 >> 8, k2 = i2 & 255;
        const float* p0 = ws + OFF_XA + (unsigned)(b0 + bl0) * 128 + k0;
        const float* p1 = ws + OFF_HE + (unsigned)rd * 65536 + (unsigned)(b0 + bl1) * 256 + k1;
        const float* p2 = ws + OFF_HE + (unsigned)rd * 65536 + (unsigned)(b0 + bl2) * 256 + k2;
        float4 q0, q1, q2;
        ld3q_sc1(q0, q1, q2, p0, p1, p2);
        *(float4*)(xbk + bl0 * 396 + k0) = q0;
        *(float4*)(xbk + bl1 * 396 + 128 + k1) = q1;
        *(float4*)(xbk + bl2 * 396 + 128 + k2) = q2;
      }
      __syncthreads();
      const int ks = tid >> 6, ml = (tid >> 2) & 15, b4 = tid & 3;
      float4 a0 = {0,0,0,0}, a1 = {0,0,0,0}, a2 = {0,0,0,0}, a3 = {0,0,0,0};
      {
        const int kbase = ks * 48;
        const float* xc0 = xbk + (b4 * 4 + 0) * 396 + kbase;
        const float* xc1 = xbk + (b4 * 4 + 1) * 396 + kbase;
        const float* xc2 = xbk + (b4 * 4 + 2) * 396 + kbase;
        const float* xc3 = xbk + (b4 * 4 + 3) * 396 + kbase;
        const float* wp  = SLAB + (unsigned)kbase * 64 + ml * 4;
#pragma unroll 8
        for (int kk = 0; kk < 48; ++kk) {
          float x0 = xc0[kk], x1 = xc1[kk], x2 = xc2[kk], x3 = xc3[kk];
          float4 wv = *(const float4*)(wp + kk * 64);
          FMA16S(a0, a1, a2, a3, x0, x1, x2, x3, wv);
        }
      }
      __syncthreads();  // xbk dead -> red
      {
        float* rp = red + (unsigned)(ks * 64 + ml * 4 + b4) * 20;
        *(float4*)(rp + 0) = a0; *(float4*)(rp + 4) = a1;
        *(float4*)(rp + 8) = a2; *(float4*)(rp + 12) = a3;
      }
      __syncthreads();
      if (tid < 256) {
        int m2 = tid & 15, bl = tid >> 4;
        int t2 = m2 * 4 + (bl >> 2), bs = bl & 3;
        float4 gate = {0,0,0,0};
#pragma unroll
        for (int k2 = 0; k2 < 8; ++k2) {
          float4 rr = *(const float4*)(red + (unsigned)(k2 * 64 + t2) * 20 + bs * 4);
          gate.x += rr.x; gate.y += rr.y; gate.z += rr.z; gate.w += rr.w;
        }
        float gi = gate.x + bsE.x, gf = gate.y + bsE.y;
        float gg = gate.z + bsE.z, go = gate.w + bsE.w;
        float cn = fast_sig(gf) * c_reg + fast_sig(gi) * fast_tanh(gg);
        float hn = fast_sig(go) * fast_tanh(cn);
        c_reg = cn;
        unsigned m = mt * 16 + m2;
        st1_sc1(ws + OFF_HE + (unsigned)wr2 * 65536 + (unsigned)(b0 + bl) * 256 + m, hn);
        st1_sc1(Xe + ((unsigned)(b0 + bl) * 64 + t) * 256 + m, hn);
        hcs[bl * 32 + m2] = hn;
        hcs[bl * 32 + 16 + m2] = cn;
      }
      __syncthreads();
      {  // S atomics: 2 batches per thread
        int j = tid & 63, wq = tid >> 6;
#pragma unroll
        for (int e2 = 0; e2 < 2; ++e2) {
          int bl2 = wq * 2 + e2;
          const float* hp = hcs + bl2 * 32;
          float s = 0.f;
#pragma unroll
          for (int q = 0; q < 4; ++q) {
            s += dot4(*(const float4*)(hp + q * 4), whc[q]);
            s += dot4(*(const float4*)(hp + 16 + q * 4), whc[4 + q]);
          }
          atomic_add_sc1(ws + OFF_SB + (unsigned)wr2 * 16384 + (unsigned)(b0 + bl2) * 64 + j, s);
        }
      }
    }
    group_barrier(barp, barn);
  }

  // ---- fill Xe row into regs: thread (m = tid&255, half = tid>>8) holds t = half*32 .. +31
  float xe[32];
  {
    int m = tid & 255, half = tid >> 8;
    const float* xb = Xe + (unsigned)bid * 16384 + (unsigned)(half * 32) * 256 + m;
#pragma unroll
    for (int g8 = 0; g8 < 4; ++g8) {
      ld8s_sc1(xe[g8*8+0], xe[g8*8+1], xe[g8*8+2], xe[g8*8+3],
               xe[g8*8+4], xe[g8*8+5], xe[g8*8+6], xe[g8*8+7],
               xb + (g8*8+0)*256, xb + (g8*8+1)*256, xb + (g8*8+2)*256,
               xb + (g8*8+3)*256, xb + (g8*8+4)*256, xb + (g8*8+5)*256,
               xb + (g8*8+6)*256, xb + (g8*8+7)*256);
    }
  }

  // ---- decoder one-time staging ----
  // PER (decoder, aliases encoder PER): vd_s[256]@0, wbt_s[257]@256, bsum_d[64]@520, wihd_s[64]@584
  float* vd_s   = PER;
  float* wbt_s  = PER + 256;
  float* bsum_d = PER + 520;
  float* wihd_s = PER + 584;
  float* wudT   = SLAB + 16384;   // [32][256] col-major WU_d slice
  __syncthreads();  // encoder PER readers done (whc/bsE already hoisted to regs)
  {
    // decoder weight slab: SLAB[k*64 + r], k < 256
    int r = tid & 63, kq = tid >> 6;
    int grow = (r & 3) * 256 + mt * 16 + (r >> 2);
#pragma unroll 4
    for (int q = 0; q < 8; ++q) {
      int k = kq * 32 + q * 4;
      float4 wv = *(const float4*)(Whh_d + grow * 256 + k);
      SLAB[(k + 0) * 64 + r] = wv.x; SLAB[(k + 1) * 64 + r] = wv.y;
      SLAB[(k + 2) * 64 + r] = wv.z; SLAB[(k + 3) * 64 + r] = wv.w;
    }
    // wudT
    {
      int j = tid & 255, half = tid >> 8;
#pragma unroll
      for (int i = 0; i < 16; ++i) {
        int c = half * 16 + i;
        int col = (c < 16) ? (mt * 16 + c) : (256 + mt * 16 + (c - 16));
        wudT[c * 256 + j] = WUd[(unsigned)j * 768 + col];
      }
    }
    if (tid < 256) vd_s[tid] = vd[tid];
    if (tid < 257) wbt_s[tid] = wbt[tid];
    if (tid < 64) {
      int g = tid >> 4, m2 = tid & 15, m = mt * 16 + m2;
      bsum_d[tid] = bih_d[g * 256 + m] + bhh_d[g * 256 + m];
      wihd_s[tid] = Wih_d[g * 256 + m];
    }
  }
  __syncthreads();

  // ---------------- P2: XeWt[bid][j][t'] = sum_k Xe[bid][t'][k] * WU_d[j][512+k]
  {
    float* XeT = SCR;          // [64][64]
    float* Wdc = SCR + 4096;   // [64][128]
    int tt2 = tid & 15, jq = tid >> 4;       // jq 0..31
    int m = tid & 255, half = tid >> 8, kk_m = m & 63;
    for (int jc = 0; jc < 2; ++jc) {
      float4 c0 = {0,0,0,0}, c1 = {0,0,0,0}, c2 = {0,0,0,0}, c3 = {0,0,0,0};
      for (int kc = 0; kc < 4; ++kc) {
        __syncthreads();
        if ((m >> 6) == kc) {
#pragma unroll
          for (int t4 = 0; t4 < 8; ++t4) {
            float4 v = { xe[t4*4+0], xe[t4*4+1], xe[t4*4+2], xe[t4*4+3] };
            *(float4*)(XeT + kk_m * 64 + half * 32 + t4 * 4) = v;
          }
        }
        {
          int jj = tid >> 2, k16 = (tid & 3) * 16;
          const float* src = WUd + (unsigned)(jc * 128 + jj) * 768 + 512 + kc * 64 + k16;
#pragma unroll
          for (int s4 = 0; s4 < 4; ++s4) {
            float4 wv = *(const float4*)(src + s4 * 4);
            Wdc[(k16 + s4*4 + 0) * 128 + jj] = wv.x;
            Wdc[(k16 + s4*4 + 1) * 128 + jj] = wv.y;
            Wdc[(k16 + s4*4 + 2) * 128 + jj] = wv.z;
            Wdc[(k16 + s4*4 + 3) * 128 + jj] = wv.w;
          }
        }
        __syncthreads();
#pragma unroll 8
        for (int kk = 0; kk < 64; ++kk) {
          float4 xv = *(const float4*)(XeT + kk * 64 + tt2 * 4);
          float4 wv = *(const float4*)(Wdc + kk * 128 + jq * 4);
          FMA16V(c0, c1, c2, c3, wv, xv);
        }
      }
      int jb = jc * 128 + jq * 4;
      *(float4*)(XeWt + ((unsigned)bid * 256 + jb + 0) * 64 + tt2 * 4) = c0;
      *(float4*)(XeWt + ((unsigned)bid * 256 + jb + 1) * 64 + tt2 * 4) = c1;
      *(float4*)(XeWt + ((unsigned)bid * 256 + jb + 2) * 64 + tt2 * 4) = c2;
      *(float4*)(XeWt + ((unsigned)bid * 256 + jb + 3) * 64 + tt2 * 4) = c3;
    }
    __syncthreads();
  }

  // hoist decoder attention weights + bias into regs
  float wreg[32];
#pragma unroll
  for (int c = 0; c < 32; ++c) wreg[c] = wudT[c * 256 + (tid & 255)];
  float4 bsD = {0,0,0,0}, wiD = {0,0,0,0};
  {
    int m2 = tid & 15;
    bsD.x = bsum_d[m2]; bsD.y = bsum_d[16 + m2]; bsD.z = bsum_d[32 + m2]; bsD.w = bsum_d[48 + m2];
    wiD.x = wihd_s[m2]; wiD.y = wihd_s[16 + m2]; wiD.z = wihd_s[32 + m2]; wiD.w = wihd_s[48 + m2];
  }
  float cd_reg = 0.f;

  // ================ DECODER: 63 steps ================
  for (int t = 0; t < 63; ++t) {
    const int rd = t & 1, wr2 = (t + 1) & 1;
    // ---- DA: temporal attention + ctx + y_tilde for b = bid
    {
      float* Sdj  = SCR;         // [256]
      float* lp   = SCR + 256;   // [8][64]
      float* beta = SCR + 768;   // [64]
      float* r8   = SCR + 832;   // [8]
      float* ctxp = SCR + 840;   // [2][256]
      if (tid < 64) {
        float* sp = ws + OFF_SDB + (unsigned)rd * 65536 + (unsigned)bid * 256 + tid * 4;
        float4 sv;
        ld1q_sc1(sv, sp);
        st1_sc1(sp + 0, 0.f); st1_sc1(sp + 1, 0.f);
        st1_sc1(sp + 2, 0.f); st1_sc1(sp + 3, 0.f);
        *(float4*)(Sdj + tid * 4) = sv;
      }
      __syncthreads();
      {
        int tq = tid & 63, q = tid >> 6;
        const float* xew = XeWt + (unsigned)bid * 16384 + tq;
        float l = 0.f;
#pragma unroll 8
        for (int jj = 0; jj < 32; ++jj) {
          int j = q * 32 + jj;
          l += vd_s[j] * fast_tanh(xew[j << 6] + Sdj[j]);
        }
        lp[q * 64 + tq] = l;
      }
      __syncthreads();
      if (tid < 64) {
        float lv = 0.f;
#pragma unroll
        for (int q = 0; q < 8; ++q) lv += lp[q * 64 + tid];
        float mx = wave_max(lv);
        float ex = __expf(lv - mx);
        float sw = wave_sum(ex);
        beta[tid] = ex / sw;
      }
      __syncthreads();
      {
        int m = tid & 255, half = tid >> 8;
        float acc = 0.f;
#pragma unroll
        for (int tt = 0; tt < 32; ++tt) acc += beta[half * 32 + tt] * xe[tt];
        ctxp[half * 256 + m] = acc;
      }
      __syncthreads();
      if (tid < 256) {
        float ctx = ctxp[tid] + ctxp[256 + tid];
        st1_sc1(ws + OFF_CTX + (unsigned)bid * 256 + tid, ctx);
        float yp = ctx * wbt_s[1 + tid];
        float swv = wave_sum(yp);
        int lane = tid & 63, wid = tid >> 6;
        if (lane == 0) r8[wid] = swv;
      }
      __syncthreads();
      if (tid == 0) {
        float yt = wbt_s[0] * in[bid * 8256 + t * 129 + 128] + r8[0] + r8[1] + r8[2] + r8[3];
        st1_sc1(ws + OFF_YT + bid, yt);
      }
    }
    group_barrier(barp, barn);

    // ---- DB: decoder gates GEMM (K=256) + pointwise + Sd atomics
    {
      float* hbk = SCR;            // [16][268]
      float* red = SCR;            // [512][20] alias
      float* hcs = SCR + 10240;    // [16][32]
      float yt_reg;
      {
        int i0 = tid * 4;          int bl0 = i0 >> 8, k0 = i0 & 255;
        int i1 = (tid + 512) * 4;  int bl1 = i1 >> 8, k1 = i1 & 255;
        const float* p0 = ws + OFF_HD + (unsigned)rd * 65536 + (unsigned)(b0 + bl0) * 256 + k0;
        const float* p1 = ws + OFF_HD + (unsigned)rd * 65536 + (unsigned)(b0 + bl1) * 256 + k1;
        const float* py = ws + OFF_YT + b0 + ((tid >> 4) & 15);
        float4 q0, q1;
        ld2q1s_sc1(q0, q1, yt_reg, p0, p1, py);
        *(float4*)(hbk + bl0 * 268 + k0) = q0;
        *(float4*)(hbk + bl1 * 268 + k1) = q1;
      }
      __syncthreads();
      const int ks = tid >> 6, ml = (tid >> 2) & 15, b4 = tid & 3;
      float4 a0 = {0,0,0,0}, a1 = {0,0,0,0}, a2 = {0,0,0,0}, a3 = {0,0,0,0};
      {
        const int kbase = ks * 32;
        const float* xc0 = hbk + (b4 * 4 + 0) * 268 + kbase;
        const float* xc1 = hbk + (b4 * 4 + 1) * 268 + kbase;
        const float* xc2 = hbk + (b4 * 4 + 2) * 268 + kbase;
        const float* xc3 = hbk + (b4 * 4 + 3) * 268 + kbase;
        const float* wp  = SLAB + (unsigned)kbase * 64 + ml * 4;
#pragma unroll 8
        for (int kk = 0; kk < 32; ++kk) {
          float x0 = xc0[kk], x1 = xc1[kk], x2 = xc2[kk], x3 = xc3[kk];
          float4 wv = *(const float4*)(wp + kk * 64);
          FMA16S(a0, a1, a2, a3, x0, x1, x2, x3, wv);
        }
      }
      __syncthreads();
      {
        float* rp = red + (unsigned)(ks * 64 + ml * 4 + b4) * 20;
        *(float4*)(rp + 0) = a0; *(float4*)(rp + 4) = a1;
        *(float4*)(rp + 8) = a2; *(float4*)(rp + 12) = a3;
      }
      __syncthreads();
      if (tid < 256) {
        int m2 = tid & 15, bl = tid >> 4;
        int t2 = m2 * 4 + (bl >> 2), bs = bl & 3;
        float4 gate = {0,0,0,0};
#pragma unroll
        for (int k2 = 0; k2 < 8; ++k2) {
          float4 rr = *(const float4*)(red + (unsigned)(k2 * 64 + t2) * 20 + bs * 4);
          gate.x += rr.x; gate.y += rr.y; gate.z += rr.z; gate.w += rr.w;
        }
        float gi = gate.x + yt_reg * wiD.x + bsD.x;
        float gf = gate.y + yt_reg * wiD.y + bsD.y;
        float gg = gate.z + yt_reg * wiD.z + bsD.z;
        float go = gate.w + yt_reg * wiD.w + bsD.w;
        float cn = fast_sig(gf) * cd_reg + fast_sig(gi) * fast_tanh(gg);
        float hn = fast_sig(go) * fast_tanh(cn);
        cd_reg = cn;
        unsigned m = mt * 16 + m2;
        st1_sc1(ws + OFF_HD + (unsigned)wr2 * 65536 + (unsigned)(b0 + bl) * 256 + m, hn);
        hcs[bl * 32 + m2] = hn;
        hcs[bl * 32 + 16 + m2] = cn;
      }
      __syncthreads();
      {  // Sd atomics: 8 batches per thread, j = tid&255
        int j = tid & 255, half = tid >> 8;
#pragma unroll
        for (int e2 = 0; e2 < 8; ++e2) {
          int bl2 = half * 8 + e2;
          const float* hp = hcs + bl2 * 32;
          float s = 0.f;
#pragma unroll
          for (int c = 0; c < 16; ++c) s += hp[c] * wreg[c];
#pragma unroll
          for (int c = 0; c < 16; ++c) s += hp[16 + c] * wreg[16 + c];
          atomic_add_sc1(ws + OFF_SDB + (unsigned)wr2 * 65536 + (unsigned)(b0 + bl2) * 256 + j, s);
        }
      }
    }
    group_barrier(barp, barn);
  }

  // ---------------- FINAL: hidden = [h_d, ctx] @ Wb_W.T + Wb_b; y = hidden @ vb_W.T + vb_b
  {
    float* hsf  = SCR;          // [16][516]
    float* hid2 = SCR + 8256;   // [2][16][17]
    {
      float4 qv[4]; const float* ps[4]; int kk[4], bb[4];
#pragma unroll
      for (int i = 0; i < 4; ++i) {
        int idx = (tid + i * 512) * 4;
        bb[i] = idx >> 9; int k = idx & 511; kk[i] = k;
        ps[i] = (k < 256)
            ? ws + OFF_HD + 65536u + (unsigned)(b0 + bb[i]) * 256 + k
            : ws + OFF_CTX + (unsigned)(b0 + bb[i]) * 256 + (k - 256);
      }
      ld4q_sc1(qv[0], qv[1], qv[2], qv[3], ps[0], ps[1], ps[2], ps[3]);
#pragma unroll
      for (int i = 0; i < 4; ++i) *(float4*)(hsf + bb[i] * 516 + kk[i]) = qv[i];
    }
    __syncthreads();
    int bl = tid & 15, p4 = (tid >> 4) & 15, half = tid >> 8;
    int row = mt * 16 + p4;
    const float* wrow = WbW + (unsigned)row * 512 + half * 256;
    const float* hp = hsf + bl * 516 + half * 256;
    float acc = half ? 0.f : Wbb[row];
#pragma unroll 8
    for (int q = 0; q < 64; ++q)
      acc += dot4(*(const float4*)(hp + q * 4), *(const float4*)(wrow + q * 4));
    hid2[half * 272 + bl * 17 + p4] = acc;
    __syncthreads();
    if (tid < 16) {
      float s = 0.f;
#pragma unroll
      for (int p = 0; p < 16; ++p)
        s += (hid2[tid * 17 + p] + hid2[272 + tid * 17 + p]) * vbW[mt * 16 + p];
      if (mt == 0) s += vbb[0];
      atomicAdd(&out[b0 + tid], s);
    }
  }
}

extern "C" void kernel_launch(void* const* d_in, const int* in_sizes, int n_in,
                              void* d_out, int out_size, void* d_ws, size_t ws_size,
                              hipStream_t stream) {
  (void)in_sizes; (void)n_in; (void)out_size; (void)ws_size;
  const float* in    = (const float*)d_in[0];
  const float* WUe   = (const float*)d_in[1];
  const float* ve    = (const float*)d_in[2];
  const float* Wih_e = (const float*)d_in[3];
  const float* Whh_e = (const float*)d_in[4];
  const float* bih_e = (const float*)d_in[5];
  const float* bhh_e = (const float*)d_in[6];
  const float* WUd   = (const float*)d_in[7];
  const float* vd    = (const float*)d_in[8];
  const float* wbt   = (const float*)d_in[9];
  const float* Wih_d = (const float*)d_in[10];
  const float* Whh_d = (const float*)d_in[11];
  const float* bih_d = (const float*)d_in[12];
  const float* bhh_d = (const float*)d_in[13];
  const float* WbW   = (const float*)d_in[14];
  const float* Wbb   = (const float*)d_in[15];
  const float* vbW   = (const float*)d_in[16];
  const float* vbb   = (const float*)d_in[17];
  float* ws  = (float*)d_ws;
  float* out = (float*)d_out;

  (void)hipFuncSetAttribute((const void*)darnn_main,
                            hipFuncAttributeMaxDynamicSharedMemorySize, SMEM_BYTES);
  hipLaunchKernelGGL(darnn_init, dim3(1024), dim3(256), 0, stream, ws, out);
  hipLaunchKernelGGL(darnn_main, dim3(256), dim3(512), SMEM_BYTES, stream,
                     in, WUe, ve, Wih_e, Whh_e, bih_e, bhh_e,
                     WUd, vd, wbt, Wih_d, Whh_d, bih_d, bhh_d,
                     WbW, Wbb, vbW, vbb, ws, out);
}